// Round 6
// baseline (866.963 us; speedup 1.0000x reference)
//
#include <hip/hip_runtime.h>
#include <hip/hip_bf16.h>

// SlidingFFAgent: fused 5-layer MLP + sliding window, bf16 MFMA pipeline.
// Round 6: depth-2 software prefetch (3-buffer compile-time rotation) in enc
// stage1/stage2 and win main loop to cover ~200-250cyc L2 latency.

#define DEVI __device__ __forceinline__

typedef float f32x4 __attribute__((ext_vector_type(4)));
typedef short s16x8 __attribute__((ext_vector_type(8)));
typedef short s16x4 __attribute__((ext_vector_type(4)));

#define ROWS 131072
#define SEQ_T 263

// packed weight offsets (in shorts)
#define W2P_OFF 524288
#define W3P_OFF 655360
#define W4P_OFF 1179648
#define W5P_OFF 1441792
#define WP_TOTAL 1458176

#define SEQ_BYTE_OFF 2916352
#define BIG_BYTE_OFF 37388288   // h3p (win output -> dec input)

DEVI short f2bf(float f) {
  union { __hip_bfloat16 h; short s; } u;
  u.h = __float2bfloat16(f);
  return u.s;
}
DEVI float bf2f(short s) {
  union { __hip_bfloat16 h; short s; } u;
  u.s = s;
  return __bfloat162float(u.h);
}

DEVI f32x4 MFMA(s16x8 a, s16x8 b, f32x4 c) {
  return __builtin_amdgcn_mfma_f32_16x16x32_bf16(a, b, c, 0, 0, 0);
}

// ---------------- weight packing: W[k][n] f32 -> frag-packed bf16 ----------------
__global__ __launch_bounds__(256) void pack_w_kernel(
    const float* __restrict__ w1, const float* __restrict__ w2,
    const float* __restrict__ w3, const float* __restrict__ w4,
    const float* __restrict__ w5, short* __restrict__ wp)
{
  int idx = blockIdx.x * 256 + threadIdx.x;
  const float* src; int sh, Nsrc, local;
  if (idx < W2P_OFF)      { src = w1; sh = 4; Nsrc = 1024; local = idx; }
  else if (idx < W3P_OFF) { src = w2; sh = 5; Nsrc = 128;  local = idx - W2P_OFF; }
  else if (idx < W4P_OFF) { src = w3; sh = 5; Nsrc = 512;  local = idx - W3P_OFF; }
  else if (idx < W5P_OFF) { src = w4; sh = 4; Nsrc = 512;  local = idx - W4P_OFF; }
  else                    { src = w5; sh = 4; Nsrc = 30;   local = idx - W5P_OFF; }
  int j    = local & 7;
  int lane = (local >> 3) & 63;
  int rest = local >> 9;
  int k0   = rest & ((1 << sh) - 1);
  int n0   = rest >> sh;
  int k = (k0 << 5) + ((lane >> 4) << 3) + j;
  int n = (n0 << 4) + (lane & 15);
  float v = (n < Nsrc) ? src[k * Nsrc + n] : 0.f;
  wp[idx] = f2bf(v);
}

// ---------------- hidden_state -> seq frames 0..6 (pre-swizzled) ----------------
__global__ __launch_bounds__(256) void hid_copy_kernel(
    const float* __restrict__ hid, short* __restrict__ seqp)
{
  int idx = blockIdx.x * 256 + threadIdx.x;   // 458752 total
  int d  = idx & 127;
  int r  = idx >> 7;
  int i  = r % 7;
  int ba = r / 7;
  int s  = (d >> 3) ^ i;
  seqp[(ba * SEQ_T + i) * 128 + s * 8 + (d & 7)] = f2bf(hid[idx]);
}

// ---------------- encoder: x2 = relu(relu(inp@w1+b1)@w2+b2) -> seq ----------------
__global__ __launch_bounds__(512, 2) void enc_kernel(
    const float* __restrict__ inp, const short* __restrict__ w1p,
    const float* __restrict__ b1, const short* __restrict__ w2p,
    const float* __restrict__ b2, short* __restrict__ seqp)
{
  __shared__ short As[32768] __attribute__((aligned(16)));   // 64x512 bf16, swizzled (64KB)
  __shared__ short h1q[32768] __attribute__((aligned(16)));  // 64x512 bf16, swizzled (64KB)
  const int tid = threadIdx.x;
  const int lane = tid & 63, wv = tid >> 6;     // wave 0..7
  const int l15 = lane & 15, lg = lane >> 4;
  const int rb = blockIdx.x << 6;

  // ---- stage A: raw f32 rows -> bf16 swizzled LDS (read HBM once) ----
  #pragma unroll
  for (int it = 0; it < 8; ++it) {
    int g = it * 512 + tid;            // 4096 x 16B chunks
    int row = g >> 6, j = g & 63;
    const float* s = inp + (long)(rb + row) * 512 + j * 8;
    f32x4 v0 = *(const f32x4*)s;
    f32x4 v1 = *(const f32x4*)(s + 4);
    s16x8 o;
    o[0]=f2bf(v0[0]); o[1]=f2bf(v0[1]); o[2]=f2bf(v0[2]); o[3]=f2bf(v0[3]);
    o[4]=f2bf(v1[0]); o[5]=f2bf(v1[1]); o[6]=f2bf(v1[2]); o[7]=f2bf(v1[3]);
    int by = ((row << 10) + (j << 4)) ^ ((row & 7) << 4);
    *(s16x8*)((char*)As + by) = o;
  }
  __syncthreads();

  f32x4 z = {0.f, 0.f, 0.f, 0.f};
  f32x4 acc2[4] = {z, z, z, z};

  for (int p = 0; p < 2; ++p) {
    // ---- stage 1: h1^T cols wv*64..+64 of pass half, depth-2 pipeline ----
    f32x4 acc1[4][4];   // [ci][mi]
    #pragma unroll
    for (int i = 0; i < 4; ++i)
      #pragma unroll
      for (int j = 0; j < 4; ++j) acc1[i][j] = z;

    const short* wB = w1p + (((p * 32 + wv * 4) * 16) << 9) + lane * 8;

    s16x8 Wb[3][4], Xb[3][4];
    #pragma unroll
    for (int ci = 0; ci < 4; ++ci) {
      Wb[0][ci] = *(const s16x8*)(wB + ((ci * 16 + 0) << 9));
      Wb[1][ci] = *(const s16x8*)(wB + ((ci * 16 + 1) << 9));
    }
    #pragma unroll
    for (int mi = 0; mi < 4; ++mi) {
      int m = mi * 16 + l15;
      int sw = (m & 7) << 4;
      int base = (m << 10) + (lg << 4);
      Xb[0][mi] = *(const s16x8*)((const char*)As + ((base + (0 << 6)) ^ sw));
      Xb[1][mi] = *(const s16x8*)((const char*)As + ((base + (1 << 6)) ^ sw));
    }

    #pragma unroll
    for (int k0 = 0; k0 < 16; ++k0) {
      const int cur = k0 % 3;
      const int pre = (k0 + 2) % 3;
      if (k0 < 14) {
        #pragma unroll
        for (int ci = 0; ci < 4; ++ci)
          Wb[pre][ci] = *(const s16x8*)(wB + ((ci * 16 + k0 + 2) << 9));
        #pragma unroll
        for (int mi = 0; mi < 4; ++mi) {
          int m = mi * 16 + l15;
          Xb[pre][mi] = *(const s16x8*)((const char*)As +
              (((m << 10) + ((k0 + 2) << 6) + (lg << 4)) ^ ((m & 7) << 4)));
        }
      }
      #pragma unroll
      for (int ci = 0; ci < 4; ++ci)
        #pragma unroll
        for (int mi = 0; mi < 4; ++mi)
          acc1[ci][mi] = MFMA(Wb[cur][ci], Xb[cur][mi], acc1[ci][mi]);
    }
    __syncthreads();  // prev pass's stage2 done reading h1q
    // ---- write h1^T (relu+b1) into h1q[m][k_local], b64 per frag ----
    #pragma unroll
    for (int ci = 0; ci < 4; ++ci) {
      f32x4 bv = *(const f32x4*)(b1 + p * 512 + wv * 64 + ci * 16 + lg * 4);
      #pragma unroll
      for (int mi = 0; mi < 4; ++mi) {
        int m = mi * 16 + l15;
        s16x4 o;
        #pragma unroll
        for (int j = 0; j < 4; ++j)
          o[j] = f2bf(fmaxf(acc1[ci][mi][j] + bv[j], 0.f));
        int by = ((m << 10) + (wv << 7) + (ci << 5) + (lg << 3)) ^ ((m & 7) << 4);
        *(s16x4*)((char*)h1q + by) = o;
      }
    }
    __syncthreads();
    // ---- stage 2: acc2 += mfma(w2frag, h1frag), depth-2 pipeline ----
    const short* w2B = w2p + ((wv * 32 + p * 16) << 9) + lane * 8;
    s16x8 W2b[3], X2b[3][4];
    W2b[0] = *(const s16x8*)(w2B);
    W2b[1] = *(const s16x8*)(w2B + (1 << 9));
    #pragma unroll
    for (int mi = 0; mi < 4; ++mi) {
      int m = mi * 16 + l15;
      int sw = (m & 7) << 4;
      int base = (m << 10) + (lg << 4);
      X2b[0][mi] = *(const s16x8*)((const char*)h1q + ((base + (0 << 6)) ^ sw));
      X2b[1][mi] = *(const s16x8*)((const char*)h1q + ((base + (1 << 6)) ^ sw));
    }
    #pragma unroll
    for (int kk = 0; kk < 16; ++kk) {
      const int cur = kk % 3;
      const int pre = (kk + 2) % 3;
      if (kk < 14) {
        W2b[pre] = *(const s16x8*)(w2B + ((kk + 2) << 9));
        #pragma unroll
        for (int mi = 0; mi < 4; ++mi) {
          int m = mi * 16 + l15;
          X2b[pre][mi] = *(const s16x8*)((const char*)h1q +
              (((m << 10) + ((kk + 2) << 6) + (lg << 4)) ^ ((m & 7) << 4)));
        }
      }
      #pragma unroll
      for (int mi = 0; mi < 4; ++mi)
        acc2[mi] = MFMA(W2b[cur], X2b[cur][mi], acc2[mi]);
    }
  }
  // ---- epilogue: x2^T frags (relu+b2) -> LDS (b64) -> coalesced seq stores ----
  __syncthreads();
  {
    f32x4 bv = *(const f32x4*)(b2 + wv * 16 + lg * 4);
    #pragma unroll
    for (int mi = 0; mi < 4; ++mi) {
      int m = mi * 16 + l15;
      s16x4 o;
      #pragma unroll
      for (int j = 0; j < 4; ++j)
        o[j] = f2bf(fmaxf(acc2[mi][j] + bv[j], 0.f));
      int by = ((m << 8) + (wv << 5) + (lg << 3)) ^ ((m & 7) << 4);
      *(s16x4*)((char*)h1q + by) = o;
    }
  }
  __syncthreads();
  #pragma unroll
  for (int it = 0; it < 2; ++it) {
    int c = it * 512 + tid;
    int s = c & 15, i = c >> 4;
    int by = ((i << 8) + (s << 4)) ^ ((i & 7) << 4);
    int r = rb + i;
    int ba2 = ((r >> 12) << 4) + (r & 15);
    int t = (r >> 4) & 255;
    int f = t + 7;
    int dst = (ba2 * SEQ_T + f) * 128 + ((s ^ (f & 7)) * 8);
    *(s16x8*)(seqp + dst) = *(const s16x8*)((const char*)h1q + by);
  }
}

// ---------------- sliding-window GEMM: h3 = relu(wins@w3+b3) -> dec A-frags ----------------
// block = (ba, th): 128 t's for one (b,a). 8 waves; 2 n-half passes, acc[4][4].
// Depth-2 global B prefetch + depth-1 LDS A prefetch, fully unrolled.
__global__ __launch_bounds__(512, 2) void win_kernel(
    const short* __restrict__ seqp, const short* __restrict__ w3p,
    const float* __restrict__ b3, short* __restrict__ h3p)
{
  __shared__ short sh[17280] __attribute__((aligned(16)));  // 135 frames (34.5KB)
  __shared__ short rp[16384] __attribute__((aligned(16)));  // 128 x 128 repack (32KB)
  const int tid = threadIdx.x;
  const int lane = tid & 63, wid = tid >> 6;
  const int wm = wid >> 2, wn = wid & 3;   // wm 0..1, wn 0..3
  const int l15 = lane & 15, lg = lane >> 4;
  const int bid = blockIdx.x;
  const int th = bid & 1, ba = bid >> 1;
  const int t0 = th << 7;

  // stage 135 frames (pre-swizzled global -> linear LDS copy keeps swizzle)
  const short* gsrc = seqp + (ba * SEQ_T + t0) * 128;
  #pragma unroll
  for (int i = 0; i < 5; ++i) {
    int c = i * 512 + tid;
    if (c < 2160) *(s16x8*)&sh[c * 8] = *(const s16x8*)(gsrc + c * 8);
  }
  __syncthreads();

  f32x4 z = {0.f, 0.f, 0.f, 0.f};
  for (int h = 0; h < 2; ++h) {
    f32x4 acc[4][4];
    #pragma unroll
    for (int i = 0; i < 4; ++i)
      #pragma unroll
      for (int j = 0; j < 4; ++j) acc[i][j] = z;

    const short* bB = w3p + (((h * 16 + wn * 4) * 32) << 9) + lane * 8;

    s16x8 Bb[3][4], Ab[2][4];
    #pragma unroll
    for (int nf = 0; nf < 4; ++nf) {
      Bb[0][nf] = *(const s16x8*)(bB + ((nf * 32 + 0) << 9));
      Bb[1][nf] = *(const s16x8*)(bB + ((nf * 32 + 1) << 9));
    }
    #pragma unroll
    for (int mf = 0; mf < 4; ++mf) {
      int f = wm * 64 + mf * 16 + l15;    // kc=0: w=0
      Ab[0][mf] = *(const s16x8*)((const char*)sh + (((f << 8) + (lg << 4)) ^ ((f & 7) << 4)));
    }

    #pragma unroll
    for (int kc = 0; kc < 32; ++kc) {
      const int curB = kc % 3;
      const int preB = (kc + 2) % 3;
      const int curA = kc & 1;
      const int preA = (kc + 1) & 1;
      if (kc < 30) {
        #pragma unroll
        for (int nf = 0; nf < 4; ++nf)
          Bb[preB][nf] = *(const s16x8*)(bB + ((nf * 32 + kc + 2) << 9));
      }
      if (kc < 31) {
        int kn = kc + 1;
        int w = kn >> 2;
        int dby = ((kn & 3) << 6) + (lg << 4);
        #pragma unroll
        for (int mf = 0; mf < 4; ++mf) {
          int f = wm * 64 + mf * 16 + l15 + w;
          Ab[preA][mf] = *(const s16x8*)((const char*)sh + (((f << 8) + dby) ^ ((f & 7) << 4)));
        }
      }
      #pragma unroll
      for (int nf = 0; nf < 4; ++nf)
        #pragma unroll
        for (int mf = 0; mf < 4; ++mf)
          acc[mf][nf] = MFMA(Ab[curA][mf], Bb[curB][nf], acc[mf][nf]);
    }

    // epilogue: 2 sub-passes of 128 cols (nf pairs {2s,2s+1})
    for (int s = 0; s < 2; ++s) {
      __syncthreads();
      #pragma unroll
      for (int mf = 0; mf < 4; ++mf)
        #pragma unroll
        for (int e = 0; e < 2; ++e) {
          int nf = s * 2 + e;
          float bias = b3[h * 256 + wn * 64 + nf * 16 + l15];
          int lc = wn * 32 + e * 16 + l15;
          #pragma unroll
          for (int rr = 0; rr < 4; ++rr) {
            int row = wm * 64 + mf * 16 + lg * 4 + rr;
            float v = fmaxf(acc[mf][nf][rr] + bias, 0.f);
            int by = ((row << 8) + (lc << 1)) ^ ((row & 7) << 4);
            rp[by >> 1] = f2bf(v);
          }
        }
      __syncthreads();
      // copy rp -> h3p, coalesced 1KB runs
      #pragma unroll
      for (int it = 0; it < 4; ++it) {
        int c = it * 512 + tid;
        int cl = c & 15, g = (c >> 4) & 3, kq = (c >> 6) & 3, tt = (c >> 8) & 7;
        int row = tt * 16 + cl;
        int by = ((row << 8) + (kq << 6) + (g << 4)) ^ ((row & 7) << 4);
        int k0g = h * 8 + kq * 2 + s;
        int mt = ba * 16 + th * 8 + tt;
        long dst = ((long)((mt * 16 + k0g) * 64 + g * 16 + cl)) << 3;
        *(s16x8*)(h3p + dst) = *(const s16x8*)((const char*)rp + by);
      }
    }
  }
}

// ---------------- decoder: q = relu(h3@w4+b4)@w5+b5 ----------------
// 128-row blocks (M-tiles = (b,a,t/16)); 8 waves; 2 n-half passes, acc[4][4].
__global__ __launch_bounds__(512, 4) void dec_kernel(
    const short* __restrict__ h3p, const short* __restrict__ w4p,
    const float* __restrict__ b4, const short* __restrict__ w5p,
    const float* __restrict__ b5, float* __restrict__ out)
{
  __shared__ short h4s[32768] __attribute__((aligned(16)));  // 128 x 256 half, swizzled
  const int tid = threadIdx.x;
  const int lane = tid & 63, wid = tid >> 6;
  const int wm = wid >> 2, wn = wid & 3;
  const int mf5 = wid;  // 0..7 for w5 stage
  const int l15 = lane & 15, lg = lane >> 4;
  const int rb = blockIdx.x << 7;

  f32x4 z = {0.f, 0.f, 0.f, 0.f};
  f32x4 acc5[2] = {z, z};
  const short* aBase = h3p + ((rb >> 4) + wm * 4) * 8192 + lane * 8;

  for (int h = 0; h < 2; ++h) {
    f32x4 acc[4][4];
    #pragma unroll
    for (int i = 0; i < 4; ++i)
      #pragma unroll
      for (int j = 0; j < 4; ++j) acc[i][j] = z;

    const short* bB = w4p + ((h * 16 + wn * 4) * 16) * 512 + lane * 8;
    s16x8 bcur[4];
    #pragma unroll
    for (int nf = 0; nf < 4; ++nf) bcur[nf] = *(const s16x8*)(bB + (nf * 16) * 512);

    #pragma unroll 1
    for (int k0 = 0; k0 < 16; ++k0) {
      int kn = (k0 + 1) & 15;
      s16x8 bnxt[4];
      #pragma unroll
      for (int nf = 0; nf < 4; ++nf) bnxt[nf] = *(const s16x8*)(bB + (nf * 16 + kn) * 512);
      s16x8 av[4];
      #pragma unroll
      for (int mf = 0; mf < 4; ++mf) av[mf] = *(const s16x8*)(aBase + mf * 8192 + k0 * 512);
      #pragma unroll
      for (int nf = 0; nf < 4; ++nf)
        #pragma unroll
        for (int mf = 0; mf < 4; ++mf)
          acc[mf][nf] = MFMA(av[mf], bcur[nf], acc[mf][nf]);
      #pragma unroll
      for (int nf = 0; nf < 4; ++nf) bcur[nf] = bnxt[nf];
    }
    __syncthreads();  // prev w5 stage done reading h4s
    #pragma unroll
    for (int mf = 0; mf < 4; ++mf)
      #pragma unroll
      for (int nf = 0; nf < 4; ++nf) {
        int lc = wn * 64 + nf * 16 + l15;
        float bias = b4[h * 256 + lc];
        #pragma unroll
        for (int rr = 0; rr < 4; ++rr) {
          int row = wm * 64 + mf * 16 + lg * 4 + rr;
          float v = fmaxf(acc[mf][nf][rr] + bias, 0.f);
          int by = ((row << 9) + (lc << 1)) ^ ((row & 7) << 4);
          h4s[by >> 1] = f2bf(v);
        }
      }
    __syncthreads();
    #pragma unroll
    for (int kk = 0; kk < 8; ++kk) {
      int row = mf5 * 16 + l15;
      int by = ((row << 9) + (kk << 6) + (lg << 4)) ^ ((row & 7) << 4);
      s16x8 a0 = *(const s16x8*)((const char*)h4s + by);
      #pragma unroll
      for (int nf = 0; nf < 2; ++nf) {
        s16x8 wb = *(const s16x8*)(w5p + (nf * 16 + h * 8 + kk) * 512 + lane * 8);
        acc5[nf] = MFMA(a0, wb, acc5[nf]);
      }
    }
  }
  #pragma unroll
  for (int nf = 0; nf < 2; ++nf) {
    int col = nf * 16 + l15;
    if (col < 30) {
      float bias = b5[col];
      #pragma unroll
      for (int rr = 0; rr < 4; ++rr) {
        int row_ = rb + mf5 * 16 + lg * 4 + rr;
        int t = row_ & 255;
        int ba2 = row_ >> 8;
        int orow = (((ba2 >> 4) << 8) + t) * 16 + (ba2 & 15);
        out[orow * 30 + col] = acc5[nf][rr] + bias;
      }
    }
  }
}

// ---------------- carried window output (unswizzle seq frames 256..262) ----------------
__global__ __launch_bounds__(256) void win_out_kernel(
    const short* __restrict__ seqp, float* __restrict__ out)
{
  int idx = blockIdx.x * 256 + threadIdx.x;  // 458752
  int d  = idx & 127;
  int r  = idx >> 7;
  int i  = r % 7;
  int ba = r / 7;
  int f = 256 + i;
  int s = (d >> 3) ^ i;
  out[3932160 + idx] = bf2f(seqp[(ba * SEQ_T + f) * 128 + s * 8 + (d & 7)]);
}

extern "C" void kernel_launch(void* const* d_in, const int* in_sizes, int n_in,
                              void* d_out, int out_size, void* d_ws, size_t ws_size,
                              hipStream_t stream) {
  const float* inp = (const float*)d_in[0];
  const float* hid = (const float*)d_in[1];
  const float* w1  = (const float*)d_in[2];
  const float* b1  = (const float*)d_in[3];
  const float* w2  = (const float*)d_in[4];
  const float* b2  = (const float*)d_in[5];
  const float* w3  = (const float*)d_in[6];
  const float* b3  = (const float*)d_in[7];
  const float* w4  = (const float*)d_in[8];
  const float* b4  = (const float*)d_in[9];
  const float* w5  = (const float*)d_in[10];
  const float* b5  = (const float*)d_in[11];

  char* ws = (char*)d_ws;
  short* wp   = (short*)ws;
  short* w1p  = wp;
  short* w2p  = wp + W2P_OFF;
  short* w3p  = wp + W3P_OFF;
  short* w4p  = wp + W4P_OFF;
  short* w5p  = wp + W5P_OFF;
  short* seqp = (short*)(ws + SEQ_BYTE_OFF);
  short* h3p  = (short*)(ws + BIG_BYTE_OFF);
  float* out  = (float*)d_out;

  pack_w_kernel  <<<WP_TOTAL / 256, 256, 0, stream>>>(w1, w2, w3, w4, w5, wp);
  hid_copy_kernel<<<1792, 256, 0, stream>>>(hid, seqp);
  enc_kernel     <<<2048, 512, 0, stream>>>(inp, w1p, b1, w2p, b2, seqp);
  win_kernel     <<<1024, 512, 0, stream>>>(seqp, w3p, b3, h3p);
  dec_kernel     <<<1024, 512, 0, stream>>>(h3p, w4p, b4, w5p, b5, out);
  win_out_kernel <<<1792, 256, 0, stream>>>(seqp, out);
}

// Round 7
// 550.651 us; speedup vs baseline: 1.5744x; 1.5744x over previous
//
#include <hip/hip_runtime.h>
#include <hip/hip_bf16.h>

// SlidingFFAgent: fused 5-layer MLP + sliding window, bf16 MFMA pipeline.
// Round 7: revert win/dec to R5; enc re-tiled for 2 blocks/CU (80KB LDS,
// 8x128-col passes, C=2xR=2 waves, depth-1 prefetch) -> TLP covers L2 latency.

#define DEVI __device__ __forceinline__

typedef float f32x4 __attribute__((ext_vector_type(4)));
typedef short s16x8 __attribute__((ext_vector_type(8)));
typedef short s16x4 __attribute__((ext_vector_type(4)));

#define ROWS 131072
#define SEQ_T 263

// packed weight offsets (in shorts)
#define W2P_OFF 524288
#define W3P_OFF 655360
#define W4P_OFF 1179648
#define W5P_OFF 1441792
#define WP_TOTAL 1458176

#define SEQ_BYTE_OFF 2916352
#define BIG_BYTE_OFF 37388288   // h3p (win output -> dec input)

DEVI short f2bf(float f) {
  union { __hip_bfloat16 h; short s; } u;
  u.h = __float2bfloat16(f);
  return u.s;
}
DEVI float bf2f(short s) {
  union { __hip_bfloat16 h; short s; } u;
  u.s = s;
  return __bfloat162float(u.h);
}

DEVI f32x4 MFMA(s16x8 a, s16x8 b, f32x4 c) {
  return __builtin_amdgcn_mfma_f32_16x16x32_bf16(a, b, c, 0, 0, 0);
}

// ---------------- weight packing: W[k][n] f32 -> frag-packed bf16 ----------------
__global__ __launch_bounds__(256) void pack_w_kernel(
    const float* __restrict__ w1, const float* __restrict__ w2,
    const float* __restrict__ w3, const float* __restrict__ w4,
    const float* __restrict__ w5, short* __restrict__ wp)
{
  int idx = blockIdx.x * 256 + threadIdx.x;
  const float* src; int sh, Nsrc, local;
  if (idx < W2P_OFF)      { src = w1; sh = 4; Nsrc = 1024; local = idx; }
  else if (idx < W3P_OFF) { src = w2; sh = 5; Nsrc = 128;  local = idx - W2P_OFF; }
  else if (idx < W4P_OFF) { src = w3; sh = 5; Nsrc = 512;  local = idx - W3P_OFF; }
  else if (idx < W5P_OFF) { src = w4; sh = 4; Nsrc = 512;  local = idx - W4P_OFF; }
  else                    { src = w5; sh = 4; Nsrc = 30;   local = idx - W5P_OFF; }
  int j    = local & 7;
  int lane = (local >> 3) & 63;
  int rest = local >> 9;
  int k0   = rest & ((1 << sh) - 1);
  int n0   = rest >> sh;
  int k = (k0 << 5) + ((lane >> 4) << 3) + j;
  int n = (n0 << 4) + (lane & 15);
  float v = (n < Nsrc) ? src[k * Nsrc + n] : 0.f;
  wp[idx] = f2bf(v);
}

// ---------------- hidden_state -> seq frames 0..6 (pre-swizzled) ----------------
__global__ __launch_bounds__(256) void hid_copy_kernel(
    const float* __restrict__ hid, short* __restrict__ seqp)
{
  int idx = blockIdx.x * 256 + threadIdx.x;   // 458752 total
  int d  = idx & 127;
  int r  = idx >> 7;
  int i  = r % 7;
  int ba = r / 7;
  int s  = (d >> 3) ^ i;
  seqp[(ba * SEQ_T + i) * 128 + s * 8 + (d & 7)] = f2bf(hid[idx]);
}

// ---------------- encoder: x2 = relu(relu(inp@w1+b1)@w2+b2) -> seq ----------------
// M=64 rows/block; A staged once into swizzled LDS (64KB); 8 passes x 128 cols
// (h1q 16KB => 80KB total => 2 blocks/CU). Waves (wm2 x wn4): C=2, R=2.
// Swapped MFMA throughout: acc = mfma(Wfrag, Xfrag) => D rows = n, cols = m.
__global__ __launch_bounds__(512, 4) void enc_kernel(
    const float* __restrict__ inp, const short* __restrict__ w1p,
    const float* __restrict__ b1, const short* __restrict__ w2p,
    const float* __restrict__ b2, short* __restrict__ seqp)
{
  __shared__ short As[32768] __attribute__((aligned(16)));   // 64x512 bf16, swizzled (64KB)
  __shared__ short h1q[8192] __attribute__((aligned(16)));   // 64x128 bf16, swizzled (16KB)
  const int tid = threadIdx.x;
  const int lane = tid & 63, wv = tid >> 6;     // wave 0..7
  const int wm = wv >> 2, wn = wv & 3;          // wm: m-half, wn: col-quarter
  const int l15 = lane & 15, lg = lane >> 4;
  const int rb = blockIdx.x << 6;

  // ---- stage A: raw f32 rows -> bf16 swizzled LDS (read HBM once) ----
  #pragma unroll
  for (int it = 0; it < 8; ++it) {
    int g = it * 512 + tid;            // 4096 x 16B chunks
    int row = g >> 6, j = g & 63;
    const float* s = inp + (long)(rb + row) * 512 + j * 8;
    f32x4 v0 = *(const f32x4*)s;
    f32x4 v1 = *(const f32x4*)(s + 4);
    s16x8 o;
    o[0]=f2bf(v0[0]); o[1]=f2bf(v0[1]); o[2]=f2bf(v0[2]); o[3]=f2bf(v0[3]);
    o[4]=f2bf(v1[0]); o[5]=f2bf(v1[1]); o[6]=f2bf(v1[2]); o[7]=f2bf(v1[3]);
    int by = ((row << 10) + (j << 4)) ^ ((row & 7) << 4);
    *(s16x8*)((char*)As + by) = o;
  }
  __syncthreads();

  f32x4 z = {0.f, 0.f, 0.f, 0.f};
  f32x4 acc2[4] = {z, z, z, z};   // wave's 16 x2-cols (col-frag wv), 4 m-frags

  const int m0 = wm * 32 + l15;       // wave's first m-frag row
  const int m1 = m0 + 16;
  const int sw0 = (m0 & 7) << 4, sw1 = (m1 & 7) << 4;

  for (int p = 0; p < 8; ++p) {
    // ---- stage 1: h1^T cols [p*128 + wn*32, +32), rows 64; C=2 x R=2 ----
    f32x4 acc1[2][2];   // [ci][mf]
    acc1[0][0] = z; acc1[0][1] = z; acc1[1][0] = z; acc1[1][1] = z;

    const short* wB = w1p + (((p * 8 + wn * 2) * 16) << 9) + lane * 8;

    s16x8 Wc0 = *(const s16x8*)(wB);
    s16x8 Wc1 = *(const s16x8*)(wB + (16 << 9));
    s16x8 Xc0 = *(const s16x8*)((const char*)As + (((m0 << 10) + (lg << 4)) ^ sw0));
    s16x8 Xc1 = *(const s16x8*)((const char*)As + (((m1 << 10) + (lg << 4)) ^ sw1));

    #pragma unroll 1
    for (int k0 = 0; k0 < 16; ++k0) {
      int kn = (k0 + 1) & 15;
      s16x8 Wn0 = *(const s16x8*)(wB + (kn << 9));
      s16x8 Wn1 = *(const s16x8*)(wB + ((16 + kn) << 9));
      s16x8 Xn0 = *(const s16x8*)((const char*)As + (((m0 << 10) + (kn << 6) + (lg << 4)) ^ sw0));
      s16x8 Xn1 = *(const s16x8*)((const char*)As + (((m1 << 10) + (kn << 6) + (lg << 4)) ^ sw1));
      acc1[0][0] = MFMA(Wc0, Xc0, acc1[0][0]);
      acc1[0][1] = MFMA(Wc0, Xc1, acc1[0][1]);
      acc1[1][0] = MFMA(Wc1, Xc0, acc1[1][0]);
      acc1[1][1] = MFMA(Wc1, Xc1, acc1[1][1]);
      Wc0 = Wn0; Wc1 = Wn1; Xc0 = Xn0; Xc1 = Xn1;
    }

    // prefetch stage-2 W2 frags for this pass (independent of LDS/barrier)
    const short* w2B = w2p + ((wv * 32 + p * 4) << 9) + lane * 8;
    s16x8 W2c[4];
    #pragma unroll
    for (int kk = 0; kk < 4; ++kk) W2c[kk] = *(const s16x8*)(w2B + (kk << 9));

    __syncthreads();  // prev pass's stage2 done reading h1q
    // ---- write h1^T (relu+b1) into h1q[m][nloc 0..128), b64 per frag ----
    #pragma unroll
    for (int ci = 0; ci < 2; ++ci) {
      f32x4 bv = *(const f32x4*)(b1 + p * 128 + wn * 32 + ci * 16 + lg * 4);
      #pragma unroll
      for (int mf = 0; mf < 2; ++mf) {
        int m = wm * 32 + mf * 16 + l15;
        s16x4 o;
        #pragma unroll
        for (int j = 0; j < 4; ++j)
          o[j] = f2bf(fmaxf(acc1[ci][mf][j] + bv[j], 0.f));
        int by = ((m << 8) + ((wn * 32 + ci * 16) << 1) + (lg << 3)) ^ ((m & 7) << 4);
        *(s16x4*)((char*)h1q + by) = o;
      }
    }
    __syncthreads();
    // ---- stage 2: acc2 += mfma(w2frag, h1frag) over this pass's 128 k ----
    #pragma unroll
    for (int kk = 0; kk < 4; ++kk) {
      #pragma unroll
      for (int mi = 0; mi < 4; ++mi) {
        int m = mi * 16 + l15;
        s16x8 X2 = *(const s16x8*)((const char*)h1q +
            (((m << 8) + (kk << 6) + (lg << 4)) ^ ((m & 7) << 4)));
        acc2[mi] = MFMA(W2c[kk], X2, acc2[mi]);
      }
    }
  }
  // ---- epilogue: x2^T frags (relu+b2) -> LDS (b64) -> coalesced seq stores ----
  __syncthreads();
  {
    f32x4 bv = *(const f32x4*)(b2 + wv * 16 + lg * 4);
    #pragma unroll
    for (int mi = 0; mi < 4; ++mi) {
      int m = mi * 16 + l15;
      s16x4 o;
      #pragma unroll
      for (int j = 0; j < 4; ++j)
        o[j] = f2bf(fmaxf(acc2[mi][j] + bv[j], 0.f));
      int by = ((m << 8) + (wv << 5) + (lg << 3)) ^ ((m & 7) << 4);
      *(s16x4*)((char*)h1q + by) = o;
    }
  }
  __syncthreads();
  #pragma unroll
  for (int it = 0; it < 2; ++it) {
    int c = it * 512 + tid;
    int s = c & 15, i = c >> 4;
    int by = ((i << 8) + (s << 4)) ^ ((i & 7) << 4);
    int r = rb + i;
    int ba2 = ((r >> 12) << 4) + (r & 15);
    int t = (r >> 4) & 255;
    int f = t + 7;
    int dst = (ba2 * SEQ_T + f) * 128 + ((s ^ (f & 7)) * 8);
    *(s16x8*)(seqp + dst) = *(const s16x8*)((const char*)h1q + by);
  }
}

// ---------------- sliding-window GEMM: h3 = relu(wins@w3+b3) -> dec A-frags ----------------
// block = (ba, th): 128 t's for one (b,a). 8 waves; 2 n-half passes, acc[4][4].
__global__ __launch_bounds__(512, 4) void win_kernel(
    const short* __restrict__ seqp, const short* __restrict__ w3p,
    const float* __restrict__ b3, short* __restrict__ h3p)
{
  __shared__ short sh[17280] __attribute__((aligned(16)));  // 135 frames (34.5KB)
  __shared__ short rp[16384] __attribute__((aligned(16)));  // 128 x 128 repack (32KB)
  const int tid = threadIdx.x;
  const int lane = tid & 63, wid = tid >> 6;
  const int wm = wid >> 2, wn = wid & 3;   // wm 0..1, wn 0..3
  const int l15 = lane & 15, lg = lane >> 4;
  const int bid = blockIdx.x;
  const int th = bid & 1, ba = bid >> 1;
  const int t0 = th << 7;

  // stage 135 frames (pre-swizzled global -> linear LDS copy keeps swizzle)
  const short* gsrc = seqp + (ba * SEQ_T + t0) * 128;
  #pragma unroll
  for (int i = 0; i < 5; ++i) {
    int c = i * 512 + tid;
    if (c < 2160) *(s16x8*)&sh[c * 8] = *(const s16x8*)(gsrc + c * 8);
  }
  __syncthreads();

  f32x4 z = {0.f, 0.f, 0.f, 0.f};
  for (int h = 0; h < 2; ++h) {
    f32x4 acc[4][4];
    #pragma unroll
    for (int i = 0; i < 4; ++i)
      #pragma unroll
      for (int j = 0; j < 4; ++j) acc[i][j] = z;

    const short* bB = w3p + ((h * 16 + wn * 4) * 32) * 512 + lane * 8;
    s16x8 bcur[4];
    #pragma unroll
    for (int nf = 0; nf < 4; ++nf) bcur[nf] = *(const s16x8*)(bB + (nf * 32) * 512);

    #pragma unroll 1
    for (int kc = 0; kc < 32; ++kc) {
      int kn = (kc + 1) & 31;
      s16x8 bnxt[4];
      #pragma unroll
      for (int nf = 0; nf < 4; ++nf) bnxt[nf] = *(const s16x8*)(bB + (nf * 32 + kn) * 512);
      int w = kc >> 2;
      int dby = ((kc & 3) << 6) + (lg << 4);
      s16x8 av[4];
      #pragma unroll
      for (int mf = 0; mf < 4; ++mf) {
        int f = wm * 64 + mf * 16 + l15 + w;
        av[mf] = *(const s16x8*)((const char*)sh + (((f << 8) + dby) ^ ((f & 7) << 4)));
      }
      #pragma unroll
      for (int nf = 0; nf < 4; ++nf)
        #pragma unroll
        for (int mf = 0; mf < 4; ++mf)
          acc[mf][nf] = MFMA(av[mf], bcur[nf], acc[mf][nf]);
      #pragma unroll
      for (int nf = 0; nf < 4; ++nf) bcur[nf] = bnxt[nf];
    }

    // epilogue: 2 sub-passes of 128 cols (nf pairs {2s,2s+1})
    for (int s = 0; s < 2; ++s) {
      __syncthreads();
      #pragma unroll
      for (int mf = 0; mf < 4; ++mf)
        #pragma unroll
        for (int e = 0; e < 2; ++e) {
          int nf = s * 2 + e;
          float bias = b3[h * 256 + wn * 64 + nf * 16 + l15];
          int lc = wn * 32 + e * 16 + l15;
          #pragma unroll
          for (int rr = 0; rr < 4; ++rr) {
            int row = wm * 64 + mf * 16 + lg * 4 + rr;
            float v = fmaxf(acc[mf][nf][rr] + bias, 0.f);
            int by = ((row << 8) + (lc << 1)) ^ ((row & 7) << 4);
            rp[by >> 1] = f2bf(v);
          }
        }
      __syncthreads();
      // copy rp -> h3p, coalesced 1KB runs
      #pragma unroll
      for (int it = 0; it < 4; ++it) {
        int c = it * 512 + tid;
        int cl = c & 15, g = (c >> 4) & 3, kq = (c >> 6) & 3, tt = (c >> 8) & 7;
        int row = tt * 16 + cl;
        int by = ((row << 8) + (kq << 6) + (g << 4)) ^ ((row & 7) << 4);
        int k0g = h * 8 + kq * 2 + s;
        int mt = ba * 16 + th * 8 + tt;
        long dst = ((long)((mt * 16 + k0g) * 64 + g * 16 + cl)) << 3;
        *(s16x8*)(h3p + dst) = *(const s16x8*)((const char*)rp + by);
      }
    }
  }
}

// ---------------- decoder: q = relu(h3@w4+b4)@w5+b5 ----------------
// 128-row blocks (M-tiles = (b,a,t/16)); 8 waves; 2 n-half passes, acc[4][4].
__global__ __launch_bounds__(512, 4) void dec_kernel(
    const short* __restrict__ h3p, const short* __restrict__ w4p,
    const float* __restrict__ b4, const short* __restrict__ w5p,
    const float* __restrict__ b5, float* __restrict__ out)
{
  __shared__ short h4s[32768] __attribute__((aligned(16)));  // 128 x 256 half, swizzled
  const int tid = threadIdx.x;
  const int lane = tid & 63, wid = tid >> 6;
  const int wm = wid >> 2, wn = wid & 3;
  const int mf5 = wid;  // 0..7 for w5 stage
  const int l15 = lane & 15, lg = lane >> 4;
  const int rb = blockIdx.x << 7;

  f32x4 z = {0.f, 0.f, 0.f, 0.f};
  f32x4 acc5[2] = {z, z};
  const short* aBase = h3p + ((rb >> 4) + wm * 4) * 8192 + lane * 8;

  for (int h = 0; h < 2; ++h) {
    f32x4 acc[4][4];
    #pragma unroll
    for (int i = 0; i < 4; ++i)
      #pragma unroll
      for (int j = 0; j < 4; ++j) acc[i][j] = z;

    const short* bB = w4p + ((h * 16 + wn * 4) * 16) * 512 + lane * 8;
    s16x8 bcur[4];
    #pragma unroll
    for (int nf = 0; nf < 4; ++nf) bcur[nf] = *(const s16x8*)(bB + (nf * 16) * 512);

    #pragma unroll 1
    for (int k0 = 0; k0 < 16; ++k0) {
      int kn = (k0 + 1) & 15;
      s16x8 bnxt[4];
      #pragma unroll
      for (int nf = 0; nf < 4; ++nf) bnxt[nf] = *(const s16x8*)(bB + (nf * 16 + kn) * 512);
      s16x8 av[4];
      #pragma unroll
      for (int mf = 0; mf < 4; ++mf) av[mf] = *(const s16x8*)(aBase + mf * 8192 + k0 * 512);
      #pragma unroll
      for (int nf = 0; nf < 4; ++nf)
        #pragma unroll
        for (int mf = 0; mf < 4; ++mf)
          acc[mf][nf] = MFMA(av[mf], bcur[nf], acc[mf][nf]);
      #pragma unroll
      for (int nf = 0; nf < 4; ++nf) bcur[nf] = bnxt[nf];
    }
    __syncthreads();  // prev w5 stage done reading h4s
    #pragma unroll
    for (int mf = 0; mf < 4; ++mf)
      #pragma unroll
      for (int nf = 0; nf < 4; ++nf) {
        int lc = wn * 64 + nf * 16 + l15;
        float bias = b4[h * 256 + lc];
        #pragma unroll
        for (int rr = 0; rr < 4; ++rr) {
          int row = wm * 64 + mf * 16 + lg * 4 + rr;
          float v = fmaxf(acc[mf][nf][rr] + bias, 0.f);
          int by = ((row << 9) + (lc << 1)) ^ ((row & 7) << 4);
          h4s[by >> 1] = f2bf(v);
        }
      }
    __syncthreads();
    #pragma unroll
    for (int kk = 0; kk < 8; ++kk) {
      int row = mf5 * 16 + l15;
      int by = ((row << 9) + (kk << 6) + (lg << 4)) ^ ((row & 7) << 4);
      s16x8 a0 = *(const s16x8*)((const char*)h4s + by);
      #pragma unroll
      for (int nf = 0; nf < 2; ++nf) {
        s16x8 wb = *(const s16x8*)(w5p + (nf * 16 + h * 8 + kk) * 512 + lane * 8);
        acc5[nf] = MFMA(a0, wb, acc5[nf]);
      }
    }
  }
  #pragma unroll
  for (int nf = 0; nf < 2; ++nf) {
    int col = nf * 16 + l15;
    if (col < 30) {
      float bias = b5[col];
      #pragma unroll
      for (int rr = 0; rr < 4; ++rr) {
        int row_ = rb + mf5 * 16 + lg * 4 + rr;
        int t = row_ & 255;
        int ba2 = row_ >> 8;
        int orow = (((ba2 >> 4) << 8) + t) * 16 + (ba2 & 15);
        out[orow * 30 + col] = acc5[nf][rr] + bias;
      }
    }
  }
}

// ---------------- carried window output (unswizzle seq frames 256..262) ----------------
__global__ __launch_bounds__(256) void win_out_kernel(
    const short* __restrict__ seqp, float* __restrict__ out)
{
  int idx = blockIdx.x * 256 + threadIdx.x;  // 458752
  int d  = idx & 127;
  int r  = idx >> 7;
  int i  = r % 7;
  int ba = r / 7;
  int f = 256 + i;
  int s = (d >> 3) ^ i;
  out[3932160 + idx] = bf2f(seqp[(ba * SEQ_T + f) * 128 + s * 8 + (d & 7)]);
}

extern "C" void kernel_launch(void* const* d_in, const int* in_sizes, int n_in,
                              void* d_out, int out_size, void* d_ws, size_t ws_size,
                              hipStream_t stream) {
  const float* inp = (const float*)d_in[0];
  const float* hid = (const float*)d_in[1];
  const float* w1  = (const float*)d_in[2];
  const float* b1  = (const float*)d_in[3];
  const float* w2  = (const float*)d_in[4];
  const float* b2  = (const float*)d_in[5];
  const float* w3  = (const float*)d_in[6];
  const float* b3  = (const float*)d_in[7];
  const float* w4  = (const float*)d_in[8];
  const float* b4  = (const float*)d_in[9];
  const float* w5  = (const float*)d_in[10];
  const float* b5  = (const float*)d_in[11];

  char* ws = (char*)d_ws;
  short* wp   = (short*)ws;
  short* w1p  = wp;
  short* w2p  = wp + W2P_OFF;
  short* w3p  = wp + W3P_OFF;
  short* w4p  = wp + W4P_OFF;
  short* w5p  = wp + W5P_OFF;
  short* seqp = (short*)(ws + SEQ_BYTE_OFF);
  short* h3p  = (short*)(ws + BIG_BYTE_OFF);
  float* out  = (float*)d_out;

  pack_w_kernel  <<<WP_TOTAL / 256, 256, 0, stream>>>(w1, w2, w3, w4, w5, wp);
  hid_copy_kernel<<<1792, 256, 0, stream>>>(hid, seqp);
  enc_kernel     <<<2048, 512, 0, stream>>>(inp, w1p, b1, w2p, b2, seqp);
  win_kernel     <<<1024, 512, 0, stream>>>(seqp, w3p, b3, h3p);
  dec_kernel     <<<1024, 512, 0, stream>>>(h3p, w4p, b4, w5p, b5, out);
  win_out_kernel <<<1792, 256, 0, stream>>>(seqp, out);
}

// Round 8
// 536.064 us; speedup vs baseline: 1.6173x; 1.0272x over previous
//
#include <hip/hip_runtime.h>
#include <hip/hip_bf16.h>

// SlidingFFAgent: fused 5-layer MLP + sliding window, bf16 MFMA pipeline.
// Round 8: enc as 16-wave (1024-thr) block, gm=1 (no w1 L2 duplication),
// C=2/R=4 per wave, P=512 passes, stage2 k-split across wave pairs with
// f32 LDS reduction. win/dec unchanged (r5/r7 structure).

#define DEVI __device__ __forceinline__

typedef float f32x4 __attribute__((ext_vector_type(4)));
typedef short s16x8 __attribute__((ext_vector_type(8)));
typedef short s16x4 __attribute__((ext_vector_type(4)));

#define ROWS 131072
#define SEQ_T 263

// packed weight offsets (in shorts)
#define W2P_OFF 524288
#define W3P_OFF 655360
#define W4P_OFF 1179648
#define W5P_OFF 1441792
#define WP_TOTAL 1458176

#define SEQ_BYTE_OFF 2916352
#define BIG_BYTE_OFF 37388288   // h3p (win output -> dec input)

DEVI short f2bf(float f) {
  union { __hip_bfloat16 h; short s; } u;
  u.h = __float2bfloat16(f);
  return u.s;
}
DEVI float bf2f(short s) {
  union { __hip_bfloat16 h; short s; } u;
  u.s = s;
  return __bfloat162float(u.h);
}

DEVI f32x4 MFMA(s16x8 a, s16x8 b, f32x4 c) {
  return __builtin_amdgcn_mfma_f32_16x16x32_bf16(a, b, c, 0, 0, 0);
}

// ---------------- weight packing: W[k][n] f32 -> frag-packed bf16 ----------------
__global__ __launch_bounds__(256) void pack_w_kernel(
    const float* __restrict__ w1, const float* __restrict__ w2,
    const float* __restrict__ w3, const float* __restrict__ w4,
    const float* __restrict__ w5, short* __restrict__ wp)
{
  int idx = blockIdx.x * 256 + threadIdx.x;
  const float* src; int sh, Nsrc, local;
  if (idx < W2P_OFF)      { src = w1; sh = 4; Nsrc = 1024; local = idx; }
  else if (idx < W3P_OFF) { src = w2; sh = 5; Nsrc = 128;  local = idx - W2P_OFF; }
  else if (idx < W4P_OFF) { src = w3; sh = 5; Nsrc = 512;  local = idx - W3P_OFF; }
  else if (idx < W5P_OFF) { src = w4; sh = 4; Nsrc = 512;  local = idx - W4P_OFF; }
  else                    { src = w5; sh = 4; Nsrc = 30;   local = idx - W5P_OFF; }
  int j    = local & 7;
  int lane = (local >> 3) & 63;
  int rest = local >> 9;
  int k0   = rest & ((1 << sh) - 1);
  int n0   = rest >> sh;
  int k = (k0 << 5) + ((lane >> 4) << 3) + j;
  int n = (n0 << 4) + (lane & 15);
  float v = (n < Nsrc) ? src[k * Nsrc + n] : 0.f;
  wp[idx] = f2bf(v);
}

// ---------------- hidden_state -> seq frames 0..6 (pre-swizzled) ----------------
__global__ __launch_bounds__(256) void hid_copy_kernel(
    const float* __restrict__ hid, short* __restrict__ seqp)
{
  int idx = blockIdx.x * 256 + threadIdx.x;   // 458752 total
  int d  = idx & 127;
  int r  = idx >> 7;
  int i  = r % 7;
  int ba = r / 7;
  int s  = (d >> 3) ^ i;
  seqp[(ba * SEQ_T + i) * 128 + s * 8 + (d & 7)] = f2bf(hid[idx]);
}

// ---------------- encoder: x2 = relu(relu(inp@w1+b1)@w2+b2) -> seq ----------------
// M=64 rows/block, 16 waves (1024 thr). A staged once in swizzled LDS (64KB).
// 2 passes x 512 h1-cols; each wave owns 32 cols (C=2,R=4), w1 read ONCE per
// block. Stage2 k-split: wave wv handles n-frag (wv&7), k-half (wv>>3);
// cross-pair f32 reduction in LDS at the end. Swapped MFMA throughout.
__global__ __launch_bounds__(1024, 4) void enc_kernel(
    const float* __restrict__ inp, const short* __restrict__ w1p,
    const float* __restrict__ b1, const short* __restrict__ w2p,
    const float* __restrict__ b2, short* __restrict__ seqp)
{
  __shared__ short As[32768] __attribute__((aligned(16)));   // 64x512 bf16, swizzled (64KB)
  __shared__ short h1q[32768] __attribute__((aligned(16)));  // 64x512 bf16, swizzled (64KB)
  const int tid = threadIdx.x;
  const int lane = tid & 63, wv = tid >> 6;     // wave 0..15
  const int l15 = lane & 15, lg = lane >> 4;
  const int nf2 = wv & 7, khalf = wv >> 3;      // stage2 roles
  const int rb = blockIdx.x << 6;

  // ---- stage A: raw f32 rows -> bf16 swizzled LDS (read HBM once) ----
  #pragma unroll
  for (int it = 0; it < 4; ++it) {
    int g = it * 1024 + tid;           // 4096 x 16B chunks
    int row = g >> 6, j = g & 63;
    const float* s = inp + (long)(rb + row) * 512 + j * 8;
    f32x4 v0 = *(const f32x4*)s;
    f32x4 v1 = *(const f32x4*)(s + 4);
    s16x8 o;
    o[0]=f2bf(v0[0]); o[1]=f2bf(v0[1]); o[2]=f2bf(v0[2]); o[3]=f2bf(v0[3]);
    o[4]=f2bf(v1[0]); o[5]=f2bf(v1[1]); o[6]=f2bf(v1[2]); o[7]=f2bf(v1[3]);
    int by = ((row << 10) + (j << 4)) ^ ((row & 7) << 4);
    *(s16x8*)((char*)As + by) = o;
  }
  __syncthreads();

  f32x4 z = {0.f, 0.f, 0.f, 0.f};
  f32x4 acc2[4] = {z, z, z, z};   // partial x2 (k-half), cols nf2*16, 4 m-frags

  for (int p = 0; p < 2; ++p) {
    // ---- stage 1: h1^T cols [p*512 + wv*32, +32), rows 64; C=2 x R=4 ----
    f32x4 acc1[2][4];   // [ci][mi]
    #pragma unroll
    for (int i = 0; i < 2; ++i)
      #pragma unroll
      for (int j = 0; j < 4; ++j) acc1[i][j] = z;

    const short* wB = w1p + (((p * 32 + wv * 2) * 16) << 9) + lane * 8;

    s16x8 Wc0 = *(const s16x8*)(wB);
    s16x8 Wc1 = *(const s16x8*)(wB + (16 << 9));
    s16x8 Xc[4];
    #pragma unroll
    for (int mi = 0; mi < 4; ++mi) {
      int m = mi * 16 + l15;
      Xc[mi] = *(const s16x8*)((const char*)As + (((m << 10) + (lg << 4)) ^ ((m & 7) << 4)));
    }

    #pragma unroll 1
    for (int k0 = 0; k0 < 16; ++k0) {
      int kn = (k0 + 1) & 15;
      s16x8 Wn0 = *(const s16x8*)(wB + (kn << 9));
      s16x8 Wn1 = *(const s16x8*)(wB + ((16 + kn) << 9));
      s16x8 Xn[4];
      #pragma unroll
      for (int mi = 0; mi < 4; ++mi) {
        int m = mi * 16 + l15;
        Xn[mi] = *(const s16x8*)((const char*)As + (((m << 10) + (kn << 6) + (lg << 4)) ^ ((m & 7) << 4)));
      }
      #pragma unroll
      for (int mi = 0; mi < 4; ++mi) {
        acc1[0][mi] = MFMA(Wc0, Xc[mi], acc1[0][mi]);
        acc1[1][mi] = MFMA(Wc1, Xc[mi], acc1[1][mi]);
      }
      Wc0 = Wn0; Wc1 = Wn1;
      #pragma unroll
      for (int mi = 0; mi < 4; ++mi) Xc[mi] = Xn[mi];
    }
    __syncthreads();  // prev pass's stage2 done reading h1q
    // ---- write h1^T (relu+b1) into h1q[m][col-in-pass], b64 per frag ----
    #pragma unroll
    for (int ci = 0; ci < 2; ++ci) {
      f32x4 bv = *(const f32x4*)(b1 + p * 512 + wv * 32 + ci * 16 + lg * 4);
      #pragma unroll
      for (int mi = 0; mi < 4; ++mi) {
        int m = mi * 16 + l15;
        s16x4 o;
        #pragma unroll
        for (int j = 0; j < 4; ++j)
          o[j] = f2bf(fmaxf(acc1[ci][mi][j] + bv[j], 0.f));
        int by = ((m << 10) + ((wv * 32 + ci * 16) << 1) + (lg << 3)) ^ ((m & 7) << 4);
        *(s16x4*)((char*)h1q + by) = o;
      }
    }
    // prefetch stage2 W2 batch0 (kk 0..3) — acc1 dead now, regs free
    const short* w2B = w2p + ((nf2 * 32 + p * 16 + khalf * 8) << 9) + lane * 8;
    s16x8 W2a[4];
    #pragma unroll
    for (int kk = 0; kk < 4; ++kk) W2a[kk] = *(const s16x8*)(w2B + (kk << 9));
    __syncthreads();
    // ---- stage 2: acc2 += mfma(w2frag, h1frag), wave's 8 k-frags ----
    s16x8 W2b[4];
    #pragma unroll
    for (int kk = 0; kk < 4; ++kk) W2b[kk] = *(const s16x8*)(w2B + ((kk + 4) << 9));
    #pragma unroll
    for (int kk = 0; kk < 4; ++kk) {
      int kf = khalf * 8 + kk;
      #pragma unroll
      for (int mi = 0; mi < 4; ++mi) {
        int m = mi * 16 + l15;
        s16x8 X2 = *(const s16x8*)((const char*)h1q +
            (((m << 10) + (kf << 6) + (lg << 4)) ^ ((m & 7) << 4)));
        acc2[mi] = MFMA(W2a[kk], X2, acc2[mi]);
      }
    }
    #pragma unroll
    for (int kk = 0; kk < 4; ++kk) {
      int kf = khalf * 8 + kk + 4;
      #pragma unroll
      for (int mi = 0; mi < 4; ++mi) {
        int m = mi * 16 + l15;
        s16x8 X2 = *(const s16x8*)((const char*)h1q +
            (((m << 10) + (kf << 6) + (lg << 4)) ^ ((m & 7) << 4)));
        acc2[mi] = MFMA(W2b[kk], X2, acc2[mi]);
      }
    }
  }
  // ---- cross-pair k-reduction + epilogue ----
  __syncthreads();   // all stage2 reads of h1q finished
  float* fbuf = (float*)h1q;            // 64x128 f32 partials (32KB)
  if (khalf == 1) {
    #pragma unroll
    for (int mi = 0; mi < 4; ++mi) {
      int m = mi * 16 + l15;
      #pragma unroll
      for (int r = 0; r < 4; ++r)
        fbuf[(nf2 * 16 + lg * 4 + r) * 64 + m] = acc2[mi][r];
    }
  }
  __syncthreads();
  short* h1q2 = h1q + 16384;            // 64x128 bf16 result (16KB)
  if (khalf == 0) {
    f32x4 bv = *(const f32x4*)(b2 + nf2 * 16 + lg * 4);
    #pragma unroll
    for (int mi = 0; mi < 4; ++mi) {
      int m = mi * 16 + l15;
      s16x4 o;
      #pragma unroll
      for (int j = 0; j < 4; ++j) {
        float v = acc2[mi][j] + fbuf[(nf2 * 16 + lg * 4 + j) * 64 + m] + bv[j];
        o[j] = f2bf(fmaxf(v, 0.f));
      }
      int by = ((m << 8) + ((nf2 * 16 + lg * 4) << 1)) ^ ((m & 7) << 4);
      *(s16x4*)((char*)h1q2 + by) = o;
    }
  }
  __syncthreads();
  {
    int c = tid;                        // 1024 x 16B chunks
    int s = c & 15, i = c >> 4;
    int by = ((i << 8) + (s << 4)) ^ ((i & 7) << 4);
    int r = rb + i;
    int ba2 = ((r >> 12) << 4) + (r & 15);
    int t = (r >> 4) & 255;
    int f = t + 7;
    int dst = (ba2 * SEQ_T + f) * 128 + ((s ^ (f & 7)) * 8);
    *(s16x8*)(seqp + dst) = *(const s16x8*)((const char*)h1q2 + by);
  }
}

// ---------------- sliding-window GEMM: h3 = relu(wins@w3+b3) -> dec A-frags ----------------
// block = (ba, th): 128 t's for one (b,a). 8 waves; 2 n-half passes, acc[4][4].
__global__ __launch_bounds__(512, 4) void win_kernel(
    const short* __restrict__ seqp, const short* __restrict__ w3p,
    const float* __restrict__ b3, short* __restrict__ h3p)
{
  __shared__ short sh[17280] __attribute__((aligned(16)));  // 135 frames (34.5KB)
  __shared__ short rp[16384] __attribute__((aligned(16)));  // 128 x 128 repack (32KB)
  const int tid = threadIdx.x;
  const int lane = tid & 63, wid = tid >> 6;
  const int wm = wid >> 2, wn = wid & 3;   // wm 0..1, wn 0..3
  const int l15 = lane & 15, lg = lane >> 4;
  const int bid = blockIdx.x;
  const int th = bid & 1, ba = bid >> 1;
  const int t0 = th << 7;

  // stage 135 frames (pre-swizzled global -> linear LDS copy keeps swizzle)
  const short* gsrc = seqp + (ba * SEQ_T + t0) * 128;
  #pragma unroll
  for (int i = 0; i < 5; ++i) {
    int c = i * 512 + tid;
    if (c < 2160) *(s16x8*)&sh[c * 8] = *(const s16x8*)(gsrc + c * 8);
  }
  __syncthreads();

  f32x4 z = {0.f, 0.f, 0.f, 0.f};
  for (int h = 0; h < 2; ++h) {
    f32x4 acc[4][4];
    #pragma unroll
    for (int i = 0; i < 4; ++i)
      #pragma unroll
      for (int j = 0; j < 4; ++j) acc[i][j] = z;

    const short* bB = w3p + ((h * 16 + wn * 4) * 32) * 512 + lane * 8;
    s16x8 bcur[4];
    #pragma unroll
    for (int nf = 0; nf < 4; ++nf) bcur[nf] = *(const s16x8*)(bB + (nf * 32) * 512);

    #pragma unroll 1
    for (int kc = 0; kc < 32; ++kc) {
      int kn = (kc + 1) & 31;
      s16x8 bnxt[4];
      #pragma unroll
      for (int nf = 0; nf < 4; ++nf) bnxt[nf] = *(const s16x8*)(bB + (nf * 32 + kn) * 512);
      int w = kc >> 2;
      int dby = ((kc & 3) << 6) + (lg << 4);
      s16x8 av[4];
      #pragma unroll
      for (int mf = 0; mf < 4; ++mf) {
        int f = wm * 64 + mf * 16 + l15 + w;
        av[mf] = *(const s16x8*)((const char*)sh + (((f << 8) + dby) ^ ((f & 7) << 4)));
      }
      #pragma unroll
      for (int nf = 0; nf < 4; ++nf)
        #pragma unroll
        for (int mf = 0; mf < 4; ++mf)
          acc[mf][nf] = MFMA(av[mf], bcur[nf], acc[mf][nf]);
      #pragma unroll
      for (int nf = 0; nf < 4; ++nf) bcur[nf] = bnxt[nf];
    }

    // epilogue: 2 sub-passes of 128 cols (nf pairs {2s,2s+1})
    for (int s = 0; s < 2; ++s) {
      __syncthreads();
      #pragma unroll
      for (int mf = 0; mf < 4; ++mf)
        #pragma unroll
        for (int e = 0; e < 2; ++e) {
          int nf = s * 2 + e;
          float bias = b3[h * 256 + wn * 64 + nf * 16 + l15];
          int lc = wn * 32 + e * 16 + l15;
          #pragma unroll
          for (int rr = 0; rr < 4; ++rr) {
            int row = wm * 64 + mf * 16 + lg * 4 + rr;
            float v = fmaxf(acc[mf][nf][rr] + bias, 0.f);
            int by = ((row << 8) + (lc << 1)) ^ ((row & 7) << 4);
            rp[by >> 1] = f2bf(v);
          }
        }
      __syncthreads();
      // copy rp -> h3p, coalesced 1KB runs
      #pragma unroll
      for (int it = 0; it < 4; ++it) {
        int c = it * 512 + tid;
        int cl = c & 15, g = (c >> 4) & 3, kq = (c >> 6) & 3, tt = (c >> 8) & 7;
        int row = tt * 16 + cl;
        int by = ((row << 8) + (kq << 6) + (g << 4)) ^ ((row & 7) << 4);
        int k0g = h * 8 + kq * 2 + s;
        int mt = ba * 16 + th * 8 + tt;
        long dst = ((long)((mt * 16 + k0g) * 64 + g * 16 + cl)) << 3;
        *(s16x8*)(h3p + dst) = *(const s16x8*)((const char*)rp + by);
      }
    }
  }
}

// ---------------- decoder: q = relu(h3@w4+b4)@w5+b5 ----------------
// 128-row blocks (M-tiles = (b,a,t/16)); 8 waves; 2 n-half passes, acc[4][4].
__global__ __launch_bounds__(512, 4) void dec_kernel(
    const short* __restrict__ h3p, const short* __restrict__ w4p,
    const float* __restrict__ b4, const short* __restrict__ w5p,
    const float* __restrict__ b5, float* __restrict__ out)
{
  __shared__ short h4s[32768] __attribute__((aligned(16)));  // 128 x 256 half, swizzled
  const int tid = threadIdx.x;
  const int lane = tid & 63, wid = tid >> 6;
  const int wm = wid >> 2, wn = wid & 3;
  const int mf5 = wid;  // 0..7 for w5 stage
  const int l15 = lane & 15, lg = lane >> 4;
  const int rb = blockIdx.x << 7;

  f32x4 z = {0.f, 0.f, 0.f, 0.f};
  f32x4 acc5[2] = {z, z};
  const short* aBase = h3p + ((rb >> 4) + wm * 4) * 8192 + lane * 8;

  for (int h = 0; h < 2; ++h) {
    f32x4 acc[4][4];
    #pragma unroll
    for (int i = 0; i < 4; ++i)
      #pragma unroll
      for (int j = 0; j < 4; ++j) acc[i][j] = z;

    const short* bB = w4p + ((h * 16 + wn * 4) * 16) * 512 + lane * 8;
    s16x8 bcur[4];
    #pragma unroll
    for (int nf = 0; nf < 4; ++nf) bcur[nf] = *(const s16x8*)(bB + (nf * 16) * 512);

    #pragma unroll 1
    for (int k0 = 0; k0 < 16; ++k0) {
      int kn = (k0 + 1) & 15;
      s16x8 bnxt[4];
      #pragma unroll
      for (int nf = 0; nf < 4; ++nf) bnxt[nf] = *(const s16x8*)(bB + (nf * 16 + kn) * 512);
      s16x8 av[4];
      #pragma unroll
      for (int mf = 0; mf < 4; ++mf) av[mf] = *(const s16x8*)(aBase + mf * 8192 + k0 * 512);
      #pragma unroll
      for (int nf = 0; nf < 4; ++nf)
        #pragma unroll
        for (int mf = 0; mf < 4; ++mf)
          acc[mf][nf] = MFMA(av[mf], bcur[nf], acc[mf][nf]);
      #pragma unroll
      for (int nf = 0; nf < 4; ++nf) bcur[nf] = bnxt[nf];
    }
    __syncthreads();  // prev w5 stage done reading h4s
    #pragma unroll
    for (int mf = 0; mf < 4; ++mf)
      #pragma unroll
      for (int nf = 0; nf < 4; ++nf) {
        int lc = wn * 64 + nf * 16 + l15;
        float bias = b4[h * 256 + lc];
        #pragma unroll
        for (int rr = 0; rr < 4; ++rr) {
          int row = wm * 64 + mf * 16 + lg * 4 + rr;
          float v = fmaxf(acc[mf][nf][rr] + bias, 0.f);
          int by = ((row << 9) + (lc << 1)) ^ ((row & 7) << 4);
          h4s[by >> 1] = f2bf(v);
        }
      }
    __syncthreads();
    #pragma unroll
    for (int kk = 0; kk < 8; ++kk) {
      int row = mf5 * 16 + l15;
      int by = ((row << 9) + (kk << 6) + (lg << 4)) ^ ((row & 7) << 4);
      s16x8 a0 = *(const s16x8*)((const char*)h4s + by);
      #pragma unroll
      for (int nf = 0; nf < 2; ++nf) {
        s16x8 wb = *(const s16x8*)(w5p + (nf * 16 + h * 8 + kk) * 512 + lane * 8);
        acc5[nf] = MFMA(a0, wb, acc5[nf]);
      }
    }
  }
  #pragma unroll
  for (int nf = 0; nf < 2; ++nf) {
    int col = nf * 16 + l15;
    if (col < 30) {
      float bias = b5[col];
      #pragma unroll
      for (int rr = 0; rr < 4; ++rr) {
        int row_ = rb + mf5 * 16 + lg * 4 + rr;
        int t = row_ & 255;
        int ba2 = row_ >> 8;
        int orow = (((ba2 >> 4) << 8) + t) * 16 + (ba2 & 15);
        out[orow * 30 + col] = acc5[nf][rr] + bias;
      }
    }
  }
}

// ---------------- carried window output (unswizzle seq frames 256..262) ----------------
__global__ __launch_bounds__(256) void win_out_kernel(
    const short* __restrict__ seqp, float* __restrict__ out)
{
  int idx = blockIdx.x * 256 + threadIdx.x;  // 458752
  int d  = idx & 127;
  int r  = idx >> 7;
  int i  = r % 7;
  int ba = r / 7;
  int f = 256 + i;
  int s = (d >> 3) ^ i;
  out[3932160 + idx] = bf2f(seqp[(ba * SEQ_T + f) * 128 + s * 8 + (d & 7)]);
}

extern "C" void kernel_launch(void* const* d_in, const int* in_sizes, int n_in,
                              void* d_out, int out_size, void* d_ws, size_t ws_size,
                              hipStream_t stream) {
  const float* inp = (const float*)d_in[0];
  const float* hid = (const float*)d_in[1];
  const float* w1  = (const float*)d_in[2];
  const float* b1  = (const float*)d_in[3];
  const float* w2  = (const float*)d_in[4];
  const float* b2  = (const float*)d_in[5];
  const float* w3  = (const float*)d_in[6];
  const float* b3  = (const float*)d_in[7];
  const float* w4  = (const float*)d_in[8];
  const float* b4  = (const float*)d_in[9];
  const float* w5  = (const float*)d_in[10];
  const float* b5  = (const float*)d_in[11];

  char* ws = (char*)d_ws;
  short* wp   = (short*)ws;
  short* w1p  = wp;
  short* w2p  = wp + W2P_OFF;
  short* w3p  = wp + W3P_OFF;
  short* w4p  = wp + W4P_OFF;
  short* w5p  = wp + W5P_OFF;
  short* seqp = (short*)(ws + SEQ_BYTE_OFF);
  short* h3p  = (short*)(ws + BIG_BYTE_OFF);
  float* out  = (float*)d_out;

  pack_w_kernel  <<<WP_TOTAL / 256, 256, 0, stream>>>(w1, w2, w3, w4, w5, wp);
  hid_copy_kernel<<<1792, 256, 0, stream>>>(hid, seqp);
  enc_kernel     <<<2048, 1024, 0, stream>>>(inp, w1p, b1, w2p, b2, seqp);
  win_kernel     <<<1024, 512, 0, stream>>>(seqp, w3p, b3, h3p);
  dec_kernel     <<<1024, 512, 0, stream>>>(h3p, w4p, b4, w5p, b5, out);
  win_out_kernel <<<1792, 256, 0, stream>>>(seqp, out);
}

// Round 9
// 526.195 us; speedup vs baseline: 1.6476x; 1.0188x over previous
//
#include <hip/hip_runtime.h>
#include <hip/hip_bf16.h>
#include <hip/hip_fp8.h>

// SlidingFFAgent: fused 5-layer MLP + sliding window, MFMA pipeline.
// Round 9: encoder in fp8 e4m3 (16x16x32_fp8_fp8): As/h1q fp8 in LDS (64KB,
// 2 blk/CU), C=4xR=4 waves (16 MFMA/k-step latency cover), conflict-free
// [k2][m] layouts. bf16 enc_hi recomputes the 7 window frames for output-1.

#define DEVI __device__ __forceinline__

typedef float f32x4 __attribute__((ext_vector_type(4)));
typedef short s16x8 __attribute__((ext_vector_type(8)));
typedef short s16x4 __attribute__((ext_vector_type(4)));
typedef long long i64;

#define ROWS 131072
#define SEQ_T 263

// packed bf16 weight offsets (in shorts) — same as r8
#define W2P_OFF 524288
#define W3P_OFF 655360
#define W4P_OFF 1179648
#define W5P_OFF 1441792
#define WP_TOTAL 1458176

#define SEQ_BYTE_OFF 2916352
#define BIG_BYTE_OFF 37388288   // h3p; its first 656KB doubles as fp8 weights for enc

DEVI short f2bf(float f) {
  union { __hip_bfloat16 h; short s; } u;
  u.h = __float2bfloat16(f);
  return u.s;
}

DEVI unsigned int f2e4(float f) {
  union { __hip_fp8_e4m3 h; unsigned char c; } u;
  u.h = __hip_fp8_e4m3(f);
  return (unsigned int)u.c;
}

DEVI f32x4 MFMA(s16x8 a, s16x8 b, f32x4 c) {
  return __builtin_amdgcn_mfma_f32_16x16x32_bf16(a, b, c, 0, 0, 0);
}
DEVI f32x4 MFMA8(i64 a, i64 b, f32x4 c) {
  return __builtin_amdgcn_mfma_f32_16x16x32_fp8_fp8(a, b, c, 0, 0, 0);
}

// ---------------- bf16 weight packing (all 5, r8 layout) ----------------
__global__ __launch_bounds__(256) void pack_w_kernel(
    const float* __restrict__ w1, const float* __restrict__ w2,
    const float* __restrict__ w3, const float* __restrict__ w4,
    const float* __restrict__ w5, short* __restrict__ wp)
{
  int idx = blockIdx.x * 256 + threadIdx.x;
  const float* src; int sh, Nsrc, local;
  if (idx < W2P_OFF)      { src = w1; sh = 4; Nsrc = 1024; local = idx; }
  else if (idx < W3P_OFF) { src = w2; sh = 5; Nsrc = 128;  local = idx - W2P_OFF; }
  else if (idx < W4P_OFF) { src = w3; sh = 5; Nsrc = 512;  local = idx - W3P_OFF; }
  else if (idx < W5P_OFF) { src = w4; sh = 4; Nsrc = 512;  local = idx - W4P_OFF; }
  else                    { src = w5; sh = 4; Nsrc = 30;   local = idx - W5P_OFF; }
  int j    = local & 7;
  int lane = (local >> 3) & 63;
  int rest = local >> 9;
  int k0   = rest & ((1 << sh) - 1);
  int n0   = rest >> sh;
  int k = (k0 << 5) + ((lane >> 4) << 3) + j;
  int n = (n0 << 4) + (lane & 15);
  float v = (n < Nsrc) ? src[k * Nsrc + n] : 0.f;
  wp[idx] = f2bf(v);
}

// ---------------- fp8 weight packing: w1, w2 -> e4m3 frag-packed ----------------
__global__ __launch_bounds__(256) void pack_w_fp8_kernel(
    const float* __restrict__ w1, const float* __restrict__ w2,
    unsigned char* __restrict__ wp8)
{
  int idx = blockIdx.x * 256 + threadIdx.x;   // 655360 total
  const float* src; int nkmask, nkshift, Nsrc, local;
  if (idx < 524288) { src = w1; local = idx;          nkmask = 15; nkshift = 4; Nsrc = 1024; }
  else              { src = w2; local = idx - 524288; nkmask = 31; nkshift = 5; Nsrc = 128; }
  int j    = local & 7;
  int lane = (local >> 3) & 63;
  int rest = local >> 9;
  int k0   = rest & nkmask;
  int n0   = rest >> nkshift;
  int k = (k0 << 5) + ((lane >> 4) << 3) + j;
  int n = (n0 << 4) + (lane & 15);
  wp8[idx] = (unsigned char)f2e4(src[k * Nsrc + n]);
}

// ---------------- hidden_state -> seq frames 0..6 (pre-swizzled) ----------------
__global__ __launch_bounds__(256) void hid_copy_kernel(
    const float* __restrict__ hid, short* __restrict__ seqp)
{
  int idx = blockIdx.x * 256 + threadIdx.x;   // 458752 total
  int d  = idx & 127;
  int r  = idx >> 7;
  int i  = r % 7;
  int ba = r / 7;
  int s  = (d >> 3) ^ i;
  seqp[(ba * SEQ_T + i) * 128 + s * 8 + (d & 7)] = f2bf(hid[idx]);
}

// ---------------- fp8 encoder: x2 = relu(relu(inp@w1+b1)@w2+b2) -> seq ----------------
// M=64/block, 8 waves. As8[k2 64][m 64]x8B (m^=(k2&7) swizzle), h1q8[k2c][m] linear.
// Stage1: 2 passes x 512 cols; wave owns 64 cols (C=4), R=4 -> 16 MFMA/k-step.
// Stage2: wave owns 16 x2-cols, full K. Swapped MFMA (D rows = n, cols = m).
__global__ __launch_bounds__(512, 4) void enc_kernel(
    const float* __restrict__ inp, const unsigned char* __restrict__ w1p8,
    const float* __restrict__ b1, const unsigned char* __restrict__ w2p8,
    const float* __restrict__ b2, short* __restrict__ seqp)
{
  __shared__ unsigned char As8[32768] __attribute__((aligned(16)));
  __shared__ unsigned char h1q8[32768] __attribute__((aligned(16)));
  const int tid = threadIdx.x;
  const int lane = tid & 63, wv = tid >> 6;     // wave 0..7
  const int l15 = lane & 15, lg = lane >> 4;
  const int rb = blockIdx.x << 6;

  // ---- stage A: f32 rows -> e4m3 LDS [k2][m], read HBM once ----
  #pragma unroll
  for (int it = 0; it < 8; ++it) {
    int g = it * 512 + tid;            // 4096 chunks of 8 elems
    int row = g >> 6, j = g & 63;      // j = k2
    const float* s = inp + (long)(rb + row) * 512 + j * 8;
    f32x4 v0 = *(const f32x4*)s;
    f32x4 v1 = *(const f32x4*)(s + 4);
    unsigned int lo = f2e4(v0[0]) | (f2e4(v0[1]) << 8) | (f2e4(v0[2]) << 16) | (f2e4(v0[3]) << 24);
    unsigned int hi = f2e4(v1[0]) | (f2e4(v1[1]) << 8) | (f2e4(v1[2]) << 16) | (f2e4(v1[3]) << 24);
    unsigned long long pk = (unsigned long long)lo | ((unsigned long long)hi << 32);
    *(unsigned long long*)(As8 + (j << 9) + ((row ^ (j & 7)) << 3)) = pk;
  }
  __syncthreads();

  f32x4 z = {0.f, 0.f, 0.f, 0.f};
  f32x4 acc2[4] = {z, z, z, z};   // x2 cols wv*16..+16, 4 m-frags, full K

  for (int p = 0; p < 2; ++p) {
    // ---- stage 1: h1^T cols [p*512 + wv*64, +64), C=4 x R=4 ----
    f32x4 acc1[4][4];   // [ci][mi]
    #pragma unroll
    for (int i = 0; i < 4; ++i)
      #pragma unroll
      for (int j = 0; j < 4; ++j) acc1[i][j] = z;

    const unsigned char* wB = w1p8 + (((p * 32 + wv * 4) * 16) << 9) + lane * 8;

    i64 Wc[4];
    #pragma unroll
    for (int ci = 0; ci < 4; ++ci) Wc[ci] = *(const i64*)(wB + ((ci * 16) << 9));

    #pragma unroll 1
    for (int k0 = 0; k0 < 16; ++k0) {
      int kn = (k0 + 1) & 15;
      i64 Wn[4];
      #pragma unroll
      for (int ci = 0; ci < 4; ++ci) Wn[ci] = *(const i64*)(wB + ((ci * 16 + kn) << 9));
      int k2 = k0 * 4 + lg;
      int c = k2 & 7;
      i64 Xc[4];
      #pragma unroll
      for (int mi = 0; mi < 4; ++mi)
        Xc[mi] = *(const i64*)(As8 + (k2 << 9) + (((mi * 16 + l15) ^ c) << 3));
      #pragma unroll
      for (int ci = 0; ci < 4; ++ci)
        #pragma unroll
        for (int mi = 0; mi < 4; ++mi)
          acc1[ci][mi] = MFMA8(Wc[ci], Xc[mi], acc1[ci][mi]);
      #pragma unroll
      for (int ci = 0; ci < 4; ++ci) Wc[ci] = Wn[ci];
    }
    __syncthreads();  // prev pass's stage2 done reading h1q8
    // ---- write h1^T (relu+b1) -> e4m3 h1q8[k2c][m], 4B per (ci,mi) ----
    #pragma unroll
    for (int ci = 0; ci < 4; ++ci) {
      f32x4 bv = *(const f32x4*)(b1 + p * 512 + wv * 64 + ci * 16 + lg * 4);
      int k2c = wv * 8 + ci * 2 + (lg >> 1);
      int half = (lg & 1) << 2;
      #pragma unroll
      for (int mi = 0; mi < 4; ++mi) {
        int m = mi * 16 + l15;
        unsigned int pk = f2e4(fmaxf(acc1[ci][mi][0] + bv[0], 0.f))
                        | (f2e4(fmaxf(acc1[ci][mi][1] + bv[1], 0.f)) << 8)
                        | (f2e4(fmaxf(acc1[ci][mi][2] + bv[2], 0.f)) << 16)
                        | (f2e4(fmaxf(acc1[ci][mi][3] + bv[3], 0.f)) << 24);
        *(unsigned int*)(h1q8 + (k2c << 9) + (m << 3) + half) = pk;
      }
    }
    __syncthreads();
    // ---- stage 2: acc2 += mfma(w2frag, h1frag), 16 k-steps this pass ----
    const unsigned char* w2B = w2p8 + ((wv * 32 + p * 16) << 9) + lane * 8;
    i64 W2c = *(const i64*)(w2B);
    #pragma unroll 1
    for (int kk = 0; kk < 16; ++kk) {
      int kn = (kk + 1) & 15;
      i64 W2n = *(const i64*)(w2B + (kn << 9));
      i64 X2[4];
      #pragma unroll
      for (int mi = 0; mi < 4; ++mi)
        X2[mi] = *(const i64*)(h1q8 + ((kk * 4 + lg) << 9) + ((mi * 16 + l15) << 3));
      #pragma unroll
      for (int mi = 0; mi < 4; ++mi)
        acc2[mi] = MFMA8(W2c, X2[mi], acc2[mi]);
      W2c = W2n;
    }
  }
  // ---- epilogue: x2^T frags (relu+b2) -> bf16 scratch -> coalesced seq stores ----
  __syncthreads();
  short* scr = (short*)As8;   // 16KB scratch (As dead)
  {
    f32x4 bv = *(const f32x4*)(b2 + wv * 16 + lg * 4);
    #pragma unroll
    for (int mi = 0; mi < 4; ++mi) {
      int m = mi * 16 + l15;
      s16x4 o;
      #pragma unroll
      for (int j = 0; j < 4; ++j)
        o[j] = f2bf(fmaxf(acc2[mi][j] + bv[j], 0.f));
      int by = ((m << 8) + ((wv * 16 + lg * 4) << 1)) ^ ((m & 7) << 4);
      *(s16x4*)((char*)scr + by) = o;
    }
  }
  __syncthreads();
  #pragma unroll
  for (int it = 0; it < 2; ++it) {
    int c = it * 512 + tid;
    int s = c & 15, i = c >> 4;
    int by = ((i << 8) + (s << 4)) ^ ((i & 7) << 4);
    int r = rb + i;
    int ba2 = ((r >> 12) << 4) + (r & 15);
    int t = (r >> 4) & 255;
    int f = t + 7;
    int dst = (ba2 * SEQ_T + f) * 128 + ((s ^ (f & 7)) * 8);
    *(s16x8*)(seqp + dst) = *(const s16x8*)((const char*)scr + by);
  }
}

// ---------------- bf16 recompute of window frames (t=249..255) -> output 1 ----------------
// block = (b, ti): 16 rows (a). Writes out[3932160 + ...] f32 directly.
__global__ __launch_bounds__(256) void enc_hi_kernel(
    const float* __restrict__ inp, const short* __restrict__ w1p,
    const float* __restrict__ b1, const short* __restrict__ w2p,
    const float* __restrict__ b2, float* __restrict__ out)
{
  __shared__ short As[8192]  __attribute__((aligned(16)));  // [k2 64][m 16] 16B
  __shared__ short h1s[16384] __attribute__((aligned(16))); // [k2c 128][m 16] 16B
  const int tid = threadIdx.x;
  const int lane = tid & 63, wv = tid >> 6;   // wave 0..3
  const int l15 = lane & 15, lg = lane >> 4;
  const int b = blockIdx.x / 7, ti = blockIdx.x % 7;
  const int t = 249 + ti;
  const long row0 = (long)b * 4096 + t * 16;

  #pragma unroll
  for (int it = 0; it < 4; ++it) {
    int c = it * 256 + tid;            // 1024 chunks (16 rows x 64)
    int m = c >> 6, j = c & 63;
    const float* s = inp + (row0 + m) * 512 + j * 8;
    f32x4 v0 = *(const f32x4*)s;
    f32x4 v1 = *(const f32x4*)(s + 4);
    s16x8 o;
    o[0]=f2bf(v0[0]); o[1]=f2bf(v0[1]); o[2]=f2bf(v0[2]); o[3]=f2bf(v0[3]);
    o[4]=f2bf(v1[0]); o[5]=f2bf(v1[1]); o[6]=f2bf(v1[2]); o[7]=f2bf(v1[3]);
    *(s16x8*)((char*)As + (j << 8) + (((m ^ (j & 15)) & 15) << 4)) = o;
  }
  __syncthreads();

  f32x4 z = {0.f, 0.f, 0.f, 0.f};
  // stage1: wave owns 256 h1 cols (C=16, R=1)
  f32x4 acc1[16];
  #pragma unroll
  for (int i = 0; i < 16; ++i) acc1[i] = z;
  #pragma unroll 1
  for (int k0 = 0; k0 < 16; ++k0) {
    int k2 = k0 * 4 + lg;
    s16x8 X = *(const s16x8*)((const char*)As + (k2 << 8) + (((l15 ^ (k2 & 15)) & 15) << 4));
    #pragma unroll
    for (int ci = 0; ci < 16; ++ci) {
      s16x8 W = *(const s16x8*)(w1p + (((wv * 16 + ci) * 16 + k0) << 9) + lane * 8);
      acc1[ci] = MFMA(W, X, acc1[ci]);
    }
  }
  // write h1 (relu+b1) -> bf16 h1s[k2c][m]
  #pragma unroll
  for (int ci = 0; ci < 16; ++ci) {
    f32x4 bv = *(const f32x4*)(b1 + wv * 256 + ci * 16 + lg * 4);
    int k2c = wv * 32 + ci * 2 + (lg >> 1);
    int half = (lg & 1) << 3;
    s16x4 o;
    #pragma unroll
    for (int j = 0; j < 4; ++j)
      o[j] = f2bf(fmaxf(acc1[ci][j] + bv[j], 0.f));
    *(s16x4*)((char*)h1s + (k2c << 8) + (l15 << 4) + half) = o;
  }
  __syncthreads();
  // stage2: wave owns 32 x2 cols (2 frags), K=1024
  f32x4 acc2[2] = {z, z};
  #pragma unroll 1
  for (int kk = 0; kk < 32; ++kk) {
    s16x8 X2 = *(const s16x8*)((const char*)h1s + ((kk * 4 + lg) << 8) + (l15 << 4));
    #pragma unroll
    for (int nf = 0; nf < 2; ++nf) {
      s16x8 W2 = *(const s16x8*)(w2p + (((wv * 2 + nf) * 32 + kk) << 9) + lane * 8);
      acc2[nf] = MFMA(W2, X2, acc2[nf]);
    }
  }
  // write x2 (relu+b2) f32 -> window output
  #pragma unroll
  for (int nf = 0; nf < 2; ++nf) {
    #pragma unroll
    for (int rr = 0; rr < 4; ++rr) {
      int d = (wv * 2 + nf) * 16 + lg * 4 + rr;
      float v = fmaxf(acc2[nf][rr] + b2[d], 0.f);
      out[3932160 + (((b * 16 + l15) * 7 + ti) << 7) + d] = v;
    }
  }
}

// ---------------- sliding-window GEMM: h3 = relu(wins@w3+b3) -> dec A-frags ----------------
__global__ __launch_bounds__(512, 4) void win_kernel(
    const short* __restrict__ seqp, const short* __restrict__ w3p,
    const float* __restrict__ b3, short* __restrict__ h3p)
{
  __shared__ short sh[17280] __attribute__((aligned(16)));
  __shared__ short rp[16384] __attribute__((aligned(16)));
  const int tid = threadIdx.x;
  const int lane = tid & 63, wid = tid >> 6;
  const int wm = wid >> 2, wn = wid & 3;
  const int l15 = lane & 15, lg = lane >> 4;
  const int bid = blockIdx.x;
  const int th = bid & 1, ba = bid >> 1;
  const int t0 = th << 7;

  const short* gsrc = seqp + (ba * SEQ_T + t0) * 128;
  #pragma unroll
  for (int i = 0; i < 5; ++i) {
    int c = i * 512 + tid;
    if (c < 2160) *(s16x8*)&sh[c * 8] = *(const s16x8*)(gsrc + c * 8);
  }
  __syncthreads();

  f32x4 z = {0.f, 0.f, 0.f, 0.f};
  for (int h = 0; h < 2; ++h) {
    f32x4 acc[4][4];
    #pragma unroll
    for (int i = 0; i < 4; ++i)
      #pragma unroll
      for (int j = 0; j < 4; ++j) acc[i][j] = z;

    const short* bB = w3p + ((h * 16 + wn * 4) * 32) * 512 + lane * 8;
    s16x8 bcur[4];
    #pragma unroll
    for (int nf = 0; nf < 4; ++nf) bcur[nf] = *(const s16x8*)(bB + (nf * 32) * 512);

    #pragma unroll 1
    for (int kc = 0; kc < 32; ++kc) {
      int kn = (kc + 1) & 31;
      s16x8 bnxt[4];
      #pragma unroll
      for (int nf = 0; nf < 4; ++nf) bnxt[nf] = *(const s16x8*)(bB + (nf * 32 + kn) * 512);
      int w = kc >> 2;
      int dby = ((kc & 3) << 6) + (lg << 4);
      s16x8 av[4];
      #pragma unroll
      for (int mf = 0; mf < 4; ++mf) {
        int f = wm * 64 + mf * 16 + l15 + w;
        av[mf] = *(const s16x8*)((const char*)sh + (((f << 8) + dby) ^ ((f & 7) << 4)));
      }
      #pragma unroll
      for (int nf = 0; nf < 4; ++nf)
        #pragma unroll
        for (int mf = 0; mf < 4; ++mf)
          acc[mf][nf] = MFMA(av[mf], bcur[nf], acc[mf][nf]);
      #pragma unroll
      for (int nf = 0; nf < 4; ++nf) bcur[nf] = bnxt[nf];
    }

    for (int s = 0; s < 2; ++s) {
      __syncthreads();
      #pragma unroll
      for (int mf = 0; mf < 4; ++mf)
        #pragma unroll
        for (int e = 0; e < 2; ++e) {
          int nf = s * 2 + e;
          float bias = b3[h * 256 + wn * 64 + nf * 16 + l15];
          int lc = wn * 32 + e * 16 + l15;
          #pragma unroll
          for (int rr = 0; rr < 4; ++rr) {
            int row = wm * 64 + mf * 16 + lg * 4 + rr;
            float v = fmaxf(acc[mf][nf][rr] + bias, 0.f);
            int by = ((row << 8) + (lc << 1)) ^ ((row & 7) << 4);
            rp[by >> 1] = f2bf(v);
          }
        }
      __syncthreads();
      #pragma unroll
      for (int it = 0; it < 4; ++it) {
        int c = it * 512 + tid;
        int cl = c & 15, g = (c >> 4) & 3, kq = (c >> 6) & 3, tt = (c >> 8) & 7;
        int row = tt * 16 + cl;
        int by = ((row << 8) + (kq << 6) + (g << 4)) ^ ((row & 7) << 4);
        int k0g = h * 8 + kq * 2 + s;
        int mt = ba * 16 + th * 8 + tt;
        long dst = ((long)((mt * 16 + k0g) * 64 + g * 16 + cl)) << 3;
        *(s16x8*)(h3p + dst) = *(const s16x8*)((const char*)rp + by);
      }
    }
  }
}

// ---------------- decoder: q = relu(h3@w4+b4)@w5+b5 ----------------
__global__ __launch_bounds__(512, 4) void dec_kernel(
    const short* __restrict__ h3p, const short* __restrict__ w4p,
    const float* __restrict__ b4, const short* __restrict__ w5p,
    const float* __restrict__ b5, float* __restrict__ out)
{
  __shared__ short h4s[32768] __attribute__((aligned(16)));
  const int tid = threadIdx.x;
  const int lane = tid & 63, wid = tid >> 6;
  const int wm = wid >> 2, wn = wid & 3;
  const int mf5 = wid;
  const int l15 = lane & 15, lg = lane >> 4;
  const int rb = blockIdx.x << 7;

  f32x4 z = {0.f, 0.f, 0.f, 0.f};
  f32x4 acc5[2] = {z, z};
  const short* aBase = h3p + ((rb >> 4) + wm * 4) * 8192 + lane * 8;

  for (int h = 0; h < 2; ++h) {
    f32x4 acc[4][4];
    #pragma unroll
    for (int i = 0; i < 4; ++i)
      #pragma unroll
      for (int j = 0; j < 4; ++j) acc[i][j] = z;

    const short* bB = w4p + ((h * 16 + wn * 4) * 16) * 512 + lane * 8;
    s16x8 bcur[4];
    #pragma unroll
    for (int nf = 0; nf < 4; ++nf) bcur[nf] = *(const s16x8*)(bB + (nf * 16) * 512);

    #pragma unroll 1
    for (int k0 = 0; k0 < 16; ++k0) {
      int kn = (k0 + 1) & 15;
      s16x8 bnxt[4];
      #pragma unroll
      for (int nf = 0; nf < 4; ++nf) bnxt[nf] = *(const s16x8*)(bB + (nf * 16 + kn) * 512);
      s16x8 av[4];
      #pragma unroll
      for (int mf = 0; mf < 4; ++mf) av[mf] = *(const s16x8*)(aBase + mf * 8192 + k0 * 512);
      #pragma unroll
      for (int nf = 0; nf < 4; ++nf)
        #pragma unroll
        for (int mf = 0; mf < 4; ++mf)
          acc[mf][nf] = MFMA(av[mf], bcur[nf], acc[mf][nf]);
      #pragma unroll
      for (int nf = 0; nf < 4; ++nf) bcur[nf] = bnxt[nf];
    }
    __syncthreads();
    #pragma unroll
    for (int mf = 0; mf < 4; ++mf)
      #pragma unroll
      for (int nf = 0; nf < 4; ++nf) {
        int lc = wn * 64 + nf * 16 + l15;
        float bias = b4[h * 256 + lc];
        #pragma unroll
        for (int rr = 0; rr < 4; ++rr) {
          int row = wm * 64 + mf * 16 + lg * 4 + rr;
          float v = fmaxf(acc[mf][nf][rr] + bias, 0.f);
          int by = ((row << 9) + (lc << 1)) ^ ((row & 7) << 4);
          h4s[by >> 1] = f2bf(v);
        }
      }
    __syncthreads();
    #pragma unroll
    for (int kk = 0; kk < 8; ++kk) {
      int row = mf5 * 16 + l15;
      int by = ((row << 9) + (kk << 6) + (lg << 4)) ^ ((row & 7) << 4);
      s16x8 a0 = *(const s16x8*)((const char*)h4s + by);
      #pragma unroll
      for (int nf = 0; nf < 2; ++nf) {
        s16x8 wb = *(const s16x8*)(w5p + (nf * 16 + h * 8 + kk) * 512 + lane * 8);
        acc5[nf] = MFMA(a0, wb, acc5[nf]);
      }
    }
  }
  #pragma unroll
  for (int nf = 0; nf < 2; ++nf) {
    int col = nf * 16 + l15;
    if (col < 30) {
      float bias = b5[col];
      #pragma unroll
      for (int rr = 0; rr < 4; ++rr) {
        int row_ = rb + mf5 * 16 + lg * 4 + rr;
        int t = row_ & 255;
        int ba2 = row_ >> 8;
        int orow = (((ba2 >> 4) << 8) + t) * 16 + (ba2 & 15);
        out[orow * 30 + col] = acc5[nf][rr] + bias;
      }
    }
  }
}

extern "C" void kernel_launch(void* const* d_in, const int* in_sizes, int n_in,
                              void* d_out, int out_size, void* d_ws, size_t ws_size,
                              hipStream_t stream) {
  const float* inp = (const float*)d_in[0];
  const float* hid = (const float*)d_in[1];
  const float* w1  = (const float*)d_in[2];
  const float* b1  = (const float*)d_in[3];
  const float* w2  = (const float*)d_in[4];
  const float* b2  = (const float*)d_in[5];
  const float* w3  = (const float*)d_in[6];
  const float* b3  = (const float*)d_in[7];
  const float* w4  = (const float*)d_in[8];
  const float* b4  = (const float*)d_in[9];
  const float* w5  = (const float*)d_in[10];
  const float* b5  = (const float*)d_in[11];

  char* ws = (char*)d_ws;
  short* wp   = (short*)ws;
  short* w1p  = wp;
  short* w2p  = wp + W2P_OFF;
  short* w3p  = wp + W3P_OFF;
  short* w4p  = wp + W4P_OFF;
  short* w5p  = wp + W5P_OFF;
  short* seqp = (short*)(ws + SEQ_BYTE_OFF);
  short* h3p  = (short*)(ws + BIG_BYTE_OFF);
  // fp8 weights live in the head of h3p (dead until win runs, after enc)
  unsigned char* w1p8 = (unsigned char*)h3p;
  unsigned char* w2p8 = w1p8 + 524288;
  float* out  = (float*)d_out;

  pack_w_kernel    <<<WP_TOTAL / 256, 256, 0, stream>>>(w1, w2, w3, w4, w5, wp);
  pack_w_fp8_kernel<<<2560, 256, 0, stream>>>(w1, w2, w1p8);
  hid_copy_kernel  <<<1792, 256, 0, stream>>>(hid, seqp);
  enc_kernel       <<<2048, 512, 0, stream>>>(inp, w1p8, b1, w2p8, b2, seqp);
  enc_hi_kernel    <<<224, 256, 0, stream>>>(inp, w1p, b1, w2p, b2, out);
  win_kernel       <<<1024, 512, 0, stream>>>(seqp, w3p, b3, h3p);
  dec_kernel       <<<1024, 512, 0, stream>>>(h3p, w4p, b4, w5p, b5, out);
}

// Round 10
// 465.853 us; speedup vs baseline: 1.8610x; 1.1295x over previous
//
#include <hip/hip_runtime.h>
#include <hip/hip_bf16.h>
#include <hip/hip_fp8.h>

// SlidingFFAgent: fused 5-layer MLP + sliding window, MFMA pipeline.
// Round 10: win in fp8 (seq stored e4m3, w3 e4m3 frags, i64 MFMA8 operands,
// 50KB LDS -> 3 blk/CU). enc epilogue + hid_copy write fp8 seq. dec unchanged.

#define DEVI __device__ __forceinline__

typedef float f32x4 __attribute__((ext_vector_type(4)));
typedef short s16x8 __attribute__((ext_vector_type(8)));
typedef short s16x4 __attribute__((ext_vector_type(4)));
typedef long long i64;

#define ROWS 131072
#define SEQ_T 263

// packed bf16 weight offsets (in shorts)
#define W2P_OFF 524288
#define W3P_OFF 655360
#define W4P_OFF 1179648
#define W5P_OFF 1441792
#define WP_TOTAL 1458176

#define W3P8_BYTE_OFF 2916352           // fp8 w3 frags (512KB)
#define SEQ8_BYTE_OFF 3440640           // fp8 seq: 512 ba x 263 x 128B = 17.2MB
#define BIG_BYTE_OFF 37388288           // h3p; head doubles as fp8 w1/w2 for enc

DEVI short f2bf(float f) {
  union { __hip_bfloat16 h; short s; } u;
  u.h = __float2bfloat16(f);
  return u.s;
}

DEVI unsigned int f2e4(float f) {
  union { __hip_fp8_e4m3 h; unsigned char c; } u;
  u.h = __hip_fp8_e4m3(f);
  return (unsigned int)u.c;
}

DEVI f32x4 MFMA(s16x8 a, s16x8 b, f32x4 c) {
  return __builtin_amdgcn_mfma_f32_16x16x32_bf16(a, b, c, 0, 0, 0);
}
DEVI f32x4 MFMA8(i64 a, i64 b, f32x4 c) {
  return __builtin_amdgcn_mfma_f32_16x16x32_fp8_fp8(a, b, c, 0, 0, 0);
}

// ---------------- bf16 weight packing (w1..w5; w1/w2 for enc_hi, w4/w5 for dec) ----------------
__global__ __launch_bounds__(256) void pack_w_kernel(
    const float* __restrict__ w1, const float* __restrict__ w2,
    const float* __restrict__ w3, const float* __restrict__ w4,
    const float* __restrict__ w5, short* __restrict__ wp)
{
  int idx = blockIdx.x * 256 + threadIdx.x;
  const float* src; int sh, Nsrc, local;
  if (idx < W2P_OFF)      { src = w1; sh = 4; Nsrc = 1024; local = idx; }
  else if (idx < W3P_OFF) { src = w2; sh = 5; Nsrc = 128;  local = idx - W2P_OFF; }
  else if (idx < W4P_OFF) { src = w3; sh = 5; Nsrc = 512;  local = idx - W3P_OFF; }
  else if (idx < W5P_OFF) { src = w4; sh = 4; Nsrc = 512;  local = idx - W4P_OFF; }
  else                    { src = w5; sh = 4; Nsrc = 30;   local = idx - W5P_OFF; }
  int j    = local & 7;
  int lane = (local >> 3) & 63;
  int rest = local >> 9;
  int k0   = rest & ((1 << sh) - 1);
  int n0   = rest >> sh;
  int k = (k0 << 5) + ((lane >> 4) << 3) + j;
  int n = (n0 << 4) + (lane & 15);
  float v = (n < Nsrc) ? src[k * Nsrc + n] : 0.f;
  wp[idx] = f2bf(v);
}

// ---------------- fp8 weight packing: w1, w2 -> wp8 ; w3 -> w3p8 ----------------
__global__ __launch_bounds__(256) void pack_w_fp8_kernel(
    const float* __restrict__ w1, const float* __restrict__ w2,
    const float* __restrict__ w3,
    unsigned char* __restrict__ wp8, unsigned char* __restrict__ w3p8)
{
  int idx = blockIdx.x * 256 + threadIdx.x;   // 1179648 total
  const float* src; int nkshift, Nsrc, local; unsigned char* dst; int doff;
  if (idx < 524288)      { src = w1; local = idx;          nkshift = 4; Nsrc = 1024; dst = wp8;  doff = idx; }
  else if (idx < 655360) { src = w2; local = idx - 524288; nkshift = 5; Nsrc = 128;  dst = wp8;  doff = idx; }
  else                   { src = w3; local = idx - 655360; nkshift = 5; Nsrc = 512;  dst = w3p8; doff = idx - 655360; }
  int j    = local & 7;
  int lane = (local >> 3) & 63;
  int rest = local >> 9;
  int k0   = rest & ((1 << nkshift) - 1);
  int n0   = rest >> nkshift;
  int k = (k0 << 5) + ((lane >> 4) << 3) + j;
  int n = (n0 << 4) + (lane & 15);
  dst[doff] = (unsigned char)f2e4(src[k * Nsrc + n]);
}

// ---------------- hidden_state -> fp8 seq frames 0..6 (pre-swizzled) ----------------
__global__ __launch_bounds__(256) void hid_copy_kernel(
    const float* __restrict__ hid, unsigned char* __restrict__ seq8)
{
  int idx = blockIdx.x * 256 + threadIdx.x;   // 458752 total
  int d  = idx & 127;
  int r  = idx >> 7;
  int i  = r % 7;
  int ba = r / 7;
  int s  = (d >> 3) ^ i;
  seq8[(ba * SEQ_T + i) * 128 + s * 8 + (d & 7)] = (unsigned char)f2e4(hid[idx]);
}

// ---------------- fp8 encoder: x2 = relu(relu(inp@w1+b1)@w2+b2) -> fp8 seq ----------------
__global__ __launch_bounds__(512, 4) void enc_kernel(
    const float* __restrict__ inp, const unsigned char* __restrict__ w1p8,
    const float* __restrict__ b1, const unsigned char* __restrict__ w2p8,
    const float* __restrict__ b2, unsigned char* __restrict__ seq8)
{
  __shared__ unsigned char As8[32768] __attribute__((aligned(16)));
  __shared__ unsigned char h1q8[32768] __attribute__((aligned(16)));
  const int tid = threadIdx.x;
  const int lane = tid & 63, wv = tid >> 6;     // wave 0..7
  const int l15 = lane & 15, lg = lane >> 4;
  const int rb = blockIdx.x << 6;

  // ---- stage A: f32 rows -> e4m3 LDS [k2][m], read HBM once ----
  #pragma unroll
  for (int it = 0; it < 8; ++it) {
    int g = it * 512 + tid;            // 4096 chunks of 8 elems
    int row = g >> 6, j = g & 63;      // j = k2
    const float* s = inp + (long)(rb + row) * 512 + j * 8;
    f32x4 v0 = *(const f32x4*)s;
    f32x4 v1 = *(const f32x4*)(s + 4);
    unsigned int lo = f2e4(v0[0]) | (f2e4(v0[1]) << 8) | (f2e4(v0[2]) << 16) | (f2e4(v0[3]) << 24);
    unsigned int hi = f2e4(v1[0]) | (f2e4(v1[1]) << 8) | (f2e4(v1[2]) << 16) | (f2e4(v1[3]) << 24);
    unsigned long long pk = (unsigned long long)lo | ((unsigned long long)hi << 32);
    *(unsigned long long*)(As8 + (j << 9) + ((row ^ (j & 7)) << 3)) = pk;
  }
  __syncthreads();

  f32x4 z = {0.f, 0.f, 0.f, 0.f};
  f32x4 acc2[4] = {z, z, z, z};   // x2 cols wv*16..+16, 4 m-frags, full K

  for (int p = 0; p < 2; ++p) {
    // ---- stage 1: h1^T cols [p*512 + wv*64, +64), C=4 x R=4 ----
    f32x4 acc1[4][4];   // [ci][mi]
    #pragma unroll
    for (int i = 0; i < 4; ++i)
      #pragma unroll
      for (int j = 0; j < 4; ++j) acc1[i][j] = z;

    const unsigned char* wB = w1p8 + (((p * 32 + wv * 4) * 16) << 9) + lane * 8;

    i64 Wc[4];
    #pragma unroll
    for (int ci = 0; ci < 4; ++ci) Wc[ci] = *(const i64*)(wB + ((ci * 16) << 9));

    #pragma unroll 1
    for (int k0 = 0; k0 < 16; ++k0) {
      int kn = (k0 + 1) & 15;
      i64 Wn[4];
      #pragma unroll
      for (int ci = 0; ci < 4; ++ci) Wn[ci] = *(const i64*)(wB + ((ci * 16 + kn) << 9));
      int k2 = k0 * 4 + lg;
      int c = k2 & 7;
      i64 Xc[4];
      #pragma unroll
      for (int mi = 0; mi < 4; ++mi)
        Xc[mi] = *(const i64*)(As8 + (k2 << 9) + (((mi * 16 + l15) ^ c) << 3));
      #pragma unroll
      for (int ci = 0; ci < 4; ++ci)
        #pragma unroll
        for (int mi = 0; mi < 4; ++mi)
          acc1[ci][mi] = MFMA8(Wc[ci], Xc[mi], acc1[ci][mi]);
      #pragma unroll
      for (int ci = 0; ci < 4; ++ci) Wc[ci] = Wn[ci];
    }
    __syncthreads();  // prev pass's stage2 done reading h1q8
    // ---- write h1^T (relu+b1) -> e4m3 h1q8[k2c][m], 4B per (ci,mi) ----
    #pragma unroll
    for (int ci = 0; ci < 4; ++ci) {
      f32x4 bv = *(const f32x4*)(b1 + p * 512 + wv * 64 + ci * 16 + lg * 4);
      int k2c = wv * 8 + ci * 2 + (lg >> 1);
      int half = (lg & 1) << 2;
      #pragma unroll
      for (int mi = 0; mi < 4; ++mi) {
        int m = mi * 16 + l15;
        unsigned int pk = f2e4(fmaxf(acc1[ci][mi][0] + bv[0], 0.f))
                        | (f2e4(fmaxf(acc1[ci][mi][1] + bv[1], 0.f)) << 8)
                        | (f2e4(fmaxf(acc1[ci][mi][2] + bv[2], 0.f)) << 16)
                        | (f2e4(fmaxf(acc1[ci][mi][3] + bv[3], 0.f)) << 24);
        *(unsigned int*)(h1q8 + (k2c << 9) + (m << 3) + half) = pk;
      }
    }
    __syncthreads();
    // ---- stage 2: acc2 += mfma(w2frag, h1frag), 16 k-steps this pass ----
    const unsigned char* w2B = w2p8 + ((wv * 32 + p * 16) << 9) + lane * 8;
    i64 W2c = *(const i64*)(w2B);
    #pragma unroll 1
    for (int kk = 0; kk < 16; ++kk) {
      int kn = (kk + 1) & 15;
      i64 W2n = *(const i64*)(w2B + (kn << 9));
      i64 X2[4];
      #pragma unroll
      for (int mi = 0; mi < 4; ++mi)
        X2[mi] = *(const i64*)(h1q8 + ((kk * 4 + lg) << 9) + ((mi * 16 + l15) << 3));
      #pragma unroll
      for (int mi = 0; mi < 4; ++mi)
        acc2[mi] = MFMA8(W2c, X2[mi], acc2[mi]);
      W2c = W2n;
    }
  }
  // ---- epilogue: x2^T (relu+b2) -> e4m3 scratch (row-swizzled) -> fp8 seq ----
  __syncthreads();
  unsigned char* scr8 = As8;   // 8KB scratch (As dead)
  {
    f32x4 bv = *(const f32x4*)(b2 + wv * 16 + lg * 4);
    int gsb = wv * 2 + (lg >> 1);
    int off4 = (lg & 1) << 2;
    #pragma unroll
    for (int mi = 0; mi < 4; ++mi) {
      int m = mi * 16 + l15;
      int f7 = ((rb >> 4) + mi + 7) & 7;
      unsigned int pk = f2e4(fmaxf(acc2[mi][0] + bv[0], 0.f))
                      | (f2e4(fmaxf(acc2[mi][1] + bv[1], 0.f)) << 8)
                      | (f2e4(fmaxf(acc2[mi][2] + bv[2], 0.f)) << 16)
                      | (f2e4(fmaxf(acc2[mi][3] + bv[3], 0.f)) << 24);
      int ls = (gsb ^ f7) ^ (m & 7);
      *(unsigned int*)(scr8 + m * 128 + ls * 8 + off4) = pk;
    }
  }
  __syncthreads();
  #pragma unroll
  for (int it = 0; it < 2; ++it) {
    int c = it * 512 + tid;
    int i = c >> 4, s = c & 15;
    unsigned long long v = *(const unsigned long long*)(scr8 + i * 128 + ((s ^ (i & 7)) << 3));
    int r = rb + i;
    int ba2 = ((r >> 12) << 4) + (r & 15);
    int t = (r >> 4) & 255;
    int f = t + 7;
    *(unsigned long long*)(seq8 + (ba2 * SEQ_T + f) * 128 + (s << 3)) = v;
  }
}

// ---------------- bf16 recompute of window frames (t=249..255) -> output 1 ----------------
__global__ __launch_bounds__(256) void enc_hi_kernel(
    const float* __restrict__ inp, const short* __restrict__ w1p,
    const float* __restrict__ b1, const short* __restrict__ w2p,
    const float* __restrict__ b2, float* __restrict__ out)
{
  __shared__ short As[8192]  __attribute__((aligned(16)));  // [k2 64][m 16] 16B
  __shared__ short h1s[16384] __attribute__((aligned(16))); // [k2c 128][m 16] 16B
  const int tid = threadIdx.x;
  const int lane = tid & 63, wv = tid >> 6;   // wave 0..3
  const int l15 = lane & 15, lg = lane >> 4;
  const int b = blockIdx.x / 7, ti = blockIdx.x % 7;
  const int t = 249 + ti;
  const long row0 = (long)b * 4096 + t * 16;

  #pragma unroll
  for (int it = 0; it < 4; ++it) {
    int c = it * 256 + tid;            // 1024 chunks (16 rows x 64)
    int m = c >> 6, j = c & 63;
    const float* s = inp + (row0 + m) * 512 + j * 8;
    f32x4 v0 = *(const f32x4*)s;
    f32x4 v1 = *(const f32x4*)(s + 4);
    s16x8 o;
    o[0]=f2bf(v0[0]); o[1]=f2bf(v0[1]); o[2]=f2bf(v0[2]); o[3]=f2bf(v0[3]);
    o[4]=f2bf(v1[0]); o[5]=f2bf(v1[1]); o[6]=f2bf(v1[2]); o[7]=f2bf(v1[3]);
    *(s16x8*)((char*)As + (j << 8) + (((m ^ (j & 15)) & 15) << 4)) = o;
  }
  __syncthreads();

  f32x4 z = {0.f, 0.f, 0.f, 0.f};
  f32x4 acc1[16];
  #pragma unroll
  for (int i = 0; i < 16; ++i) acc1[i] = z;
  #pragma unroll 1
  for (int k0 = 0; k0 < 16; ++k0) {
    int k2 = k0 * 4 + lg;
    s16x8 X = *(const s16x8*)((const char*)As + (k2 << 8) + (((l15 ^ (k2 & 15)) & 15) << 4));
    #pragma unroll
    for (int ci = 0; ci < 16; ++ci) {
      s16x8 W = *(const s16x8*)(w1p + (((wv * 16 + ci) * 16 + k0) << 9) + lane * 8);
      acc1[ci] = MFMA(W, X, acc1[ci]);
    }
  }
  #pragma unroll
  for (int ci = 0; ci < 16; ++ci) {
    f32x4 bv = *(const f32x4*)(b1 + wv * 256 + ci * 16 + lg * 4);
    int k2c = wv * 32 + ci * 2 + (lg >> 1);
    int half = (lg & 1) << 3;
    s16x4 o;
    #pragma unroll
    for (int j = 0; j < 4; ++j)
      o[j] = f2bf(fmaxf(acc1[ci][j] + bv[j], 0.f));
    *(s16x4*)((char*)h1s + (k2c << 8) + (l15 << 4) + half) = o;
  }
  __syncthreads();
  f32x4 acc2[2] = {z, z};
  #pragma unroll 1
  for (int kk = 0; kk < 32; ++kk) {
    s16x8 X2 = *(const s16x8*)((const char*)h1s + ((kk * 4 + lg) << 8) + (l15 << 4));
    #pragma unroll
    for (int nf = 0; nf < 2; ++nf) {
      s16x8 W2 = *(const s16x8*)(w2p + (((wv * 2 + nf) * 32 + kk) << 9) + lane * 8);
      acc2[nf] = MFMA(W2, X2, acc2[nf]);
    }
  }
  #pragma unroll
  for (int nf = 0; nf < 2; ++nf) {
    #pragma unroll
    for (int rr = 0; rr < 4; ++rr) {
      int d = (wv * 2 + nf) * 16 + lg * 4 + rr;
      float v = fmaxf(acc2[nf][rr] + b2[d], 0.f);
      out[3932160 + (((b * 16 + l15) * 7 + ti) << 7) + d] = v;
    }
  }
}

// ---------------- fp8 sliding-window GEMM: h3 = relu(wins@w3+b3) -> dec A-frags ----------------
// block = (ba, th). 8 waves; 2 n-half passes, acc[4][4]; A from fp8 seq LDS,
// B from fp8 w3 frags (i64), output bf16 via rp -> h3p (unchanged layout).
__global__ __launch_bounds__(512, 4) void win_kernel(
    const unsigned char* __restrict__ seq8, const unsigned char* __restrict__ w3p8,
    const float* __restrict__ b3, short* __restrict__ h3p)
{
  __shared__ unsigned char sh8[17280] __attribute__((aligned(16)));  // 135 frames x 128B
  __shared__ short rp[16384] __attribute__((aligned(16)));           // 128x128 bf16 repack
  const int tid = threadIdx.x;
  const int lane = tid & 63, wid = tid >> 6;
  const int wm = wid >> 2, wn = wid & 3;
  const int l15 = lane & 15, lg = lane >> 4;
  const int bid = blockIdx.x;
  const int th = bid & 1, ba = bid >> 1;
  const int t0 = th << 7;

  // stage 135 fp8 frames (pre-swizzled global -> linear LDS copy keeps swizzle)
  const unsigned char* gsrc = seq8 + (ba * SEQ_T + t0) * 128;
  #pragma unroll
  for (int i = 0; i < 3; ++i) {
    int c = i * 512 + tid;
    if (c < 1080) *(s16x8*)&sh8[c * 16] = *(const s16x8*)(gsrc + c * 16);
  }
  __syncthreads();

  f32x4 z = {0.f, 0.f, 0.f, 0.f};
  for (int h = 0; h < 2; ++h) {
    f32x4 acc[4][4];
    #pragma unroll
    for (int i = 0; i < 4; ++i)
      #pragma unroll
      for (int j = 0; j < 4; ++j) acc[i][j] = z;

    const unsigned char* bB = w3p8 + (((h * 16 + wn * 4) * 32) << 9) + lane * 8;
    i64 bcur[4];
    #pragma unroll
    for (int nf = 0; nf < 4; ++nf) bcur[nf] = *(const i64*)(bB + ((nf * 32) << 9));

    #pragma unroll 1
    for (int kc = 0; kc < 32; ++kc) {
      int kn = (kc + 1) & 31;
      i64 bnxt[4];
      #pragma unroll
      for (int nf = 0; nf < 4; ++nf) bnxt[nf] = *(const i64*)(bB + ((nf * 32 + kn) << 9));
      int w = kc >> 2;
      int dslot = ((kc & 3) << 2) + lg;
      i64 av[4];
      #pragma unroll
      for (int mf = 0; mf < 4; ++mf) {
        int f = wm * 64 + mf * 16 + l15 + w;
        av[mf] = *(const i64*)(sh8 + f * 128 + ((dslot ^ (f & 7)) << 3));
      }
      #pragma unroll
      for (int nf = 0; nf < 4; ++nf)
        #pragma unroll
        for (int mf = 0; mf < 4; ++mf)
          acc[mf][nf] = MFMA8(av[mf], bcur[nf], acc[mf][nf]);
      #pragma unroll
      for (int nf = 0; nf < 4; ++nf) bcur[nf] = bnxt[nf];
    }

    // epilogue: 2 sub-passes of 128 cols (nf pairs {2s,2s+1})
    for (int s = 0; s < 2; ++s) {
      __syncthreads();
      #pragma unroll
      for (int mf = 0; mf < 4; ++mf)
        #pragma unroll
        for (int e = 0; e < 2; ++e) {
          int nf = s * 2 + e;
          float bias = b3[h * 256 + wn * 64 + nf * 16 + l15];
          int lc = wn * 32 + e * 16 + l15;
          #pragma unroll
          for (int rr = 0; rr < 4; ++rr) {
            int row = wm * 64 + mf * 16 + lg * 4 + rr;
            float v = fmaxf(acc[mf][nf][rr] + bias, 0.f);
            int by = ((row << 8) + (lc << 1)) ^ ((row & 7) << 4);
            rp[by >> 1] = f2bf(v);
          }
        }
      __syncthreads();
      #pragma unroll
      for (int it = 0; it < 4; ++it) {
        int c = it * 512 + tid;
        int cl = c & 15, g = (c >> 4) & 3, kq = (c >> 6) & 3, tt = (c >> 8) & 7;
        int row = tt * 16 + cl;
        int by = ((row << 8) + (kq << 6) + (g << 4)) ^ ((row & 7) << 4);
        int k0g = h * 8 + kq * 2 + s;
        int mt = ba * 16 + th * 8 + tt;
        long dst = ((long)((mt * 16 + k0g) * 64 + g * 16 + cl)) << 3;
        *(s16x8*)(h3p + dst) = *(const s16x8*)((const char*)rp + by);
      }
    }
  }
}

// ---------------- decoder: q = relu(h3@w4+b4)@w5+b5 ----------------
__global__ __launch_bounds__(512, 4) void dec_kernel(
    const short* __restrict__ h3p, const short* __restrict__ w4p,
    const float* __restrict__ b4, const short* __restrict__ w5p,
    const float* __restrict__ b5, float* __restrict__ out)
{
  __shared__ short h4s[32768] __attribute__((aligned(16)));
  const int tid = threadIdx.x;
  const int lane = tid & 63, wid = tid >> 6;
  const int wm = wid >> 2, wn = wid & 3;
  const int mf5 = wid;
  const int l15 = lane & 15, lg = lane >> 4;
  const int rb = blockIdx.x << 7;

  f32x4 z = {0.f, 0.f, 0.f, 0.f};
  f32x4 acc5[2] = {z, z};
  const short* aBase = h3p + ((rb >> 4) + wm * 4) * 8192 + lane * 8;

  for (int h = 0; h < 2; ++h) {
    f32x4 acc[4][4];
    #pragma unroll
    for (int i = 0; i < 4; ++i)
      #pragma unroll
      for (int j = 0; j < 4; ++j) acc[i][j] = z;

    const short* bB = w4p + ((h * 16 + wn * 4) * 16) * 512 + lane * 8;
    s16x8 bcur[4];
    #pragma unroll
    for (int nf = 0; nf < 4; ++nf) bcur[nf] = *(const s16x8*)(bB + (nf * 16) * 512);

    #pragma unroll 1
    for (int k0 = 0; k0 < 16; ++k0) {
      int kn = (k0 + 1) & 15;
      s16x8 bnxt[4];
      #pragma unroll
      for (int nf = 0; nf < 4; ++nf) bnxt[nf] = *(const s16x8*)(bB + (nf * 16 + kn) * 512);
      s16x8 av[4];
      #pragma unroll
      for (int mf = 0; mf < 4; ++mf) av[mf] = *(const s16x8*)(aBase + mf * 8192 + k0 * 512);
      #pragma unroll
      for (int nf = 0; nf < 4; ++nf)
        #pragma unroll
        for (int mf = 0; mf < 4; ++mf)
          acc[mf][nf] = MFMA(av[mf], bcur[nf], acc[mf][nf]);
      #pragma unroll
      for (int nf = 0; nf < 4; ++nf) bcur[nf] = bnxt[nf];
    }
    __syncthreads();
    #pragma unroll
    for (int mf = 0; mf < 4; ++mf)
      #pragma unroll
      for (int nf = 0; nf < 4; ++nf) {
        int lc = wn * 64 + nf * 16 + l15;
        float bias = b4[h * 256 + lc];
        #pragma unroll
        for (int rr = 0; rr < 4; ++rr) {
          int row = wm * 64 + mf * 16 + lg * 4 + rr;
          float v = fmaxf(acc[mf][nf][rr] + bias, 0.f);
          int by = ((row << 9) + (lc << 1)) ^ ((row & 7) << 4);
          h4s[by >> 1] = f2bf(v);
        }
      }
    __syncthreads();
    #pragma unroll
    for (int kk = 0; kk < 8; ++kk) {
      int row = mf5 * 16 + l15;
      int by = ((row << 9) + (kk << 6) + (lg << 4)) ^ ((row & 7) << 4);
      s16x8 a0 = *(const s16x8*)((const char*)h4s + by);
      #pragma unroll
      for (int nf = 0; nf < 2; ++nf) {
        s16x8 wb = *(const s16x8*)(w5p + (nf * 16 + h * 8 + kk) * 512 + lane * 8);
        acc5[nf] = MFMA(a0, wb, acc5[nf]);
      }
    }
  }
  #pragma unroll
  for (int nf = 0; nf < 2; ++nf) {
    int col = nf * 16 + l15;
    if (col < 30) {
      float bias = b5[col];
      #pragma unroll
      for (int rr = 0; rr < 4; ++rr) {
        int row_ = rb + mf5 * 16 + lg * 4 + rr;
        int t = row_ & 255;
        int ba2 = row_ >> 8;
        int orow = (((ba2 >> 4) << 8) + t) * 16 + (ba2 & 15);
        out[orow * 30 + col] = acc5[nf][rr] + bias;
      }
    }
  }
}

extern "C" void kernel_launch(void* const* d_in, const int* in_sizes, int n_in,
                              void* d_out, int out_size, void* d_ws, size_t ws_size,
                              hipStream_t stream) {
  const float* inp = (const float*)d_in[0];
  const float* hid = (const float*)d_in[1];
  const float* w1  = (const float*)d_in[2];
  const float* b1  = (const float*)d_in[3];
  const float* w2  = (const float*)d_in[4];
  const float* b2  = (const float*)d_in[5];
  const float* w3  = (const float*)d_in[6];
  const float* b3  = (const float*)d_in[7];
  const float* w4  = (const float*)d_in[8];
  const float* b4  = (const float*)d_in[9];
  const float* w5  = (const float*)d_in[10];
  const float* b5  = (const float*)d_in[11];

  char* ws = (char*)d_ws;
  short* wp   = (short*)ws;
  short* w1p  = wp;
  short* w2p  = wp + W2P_OFF;
  short* w4p  = wp + W4P_OFF;
  short* w5p  = wp + W5P_OFF;
  unsigned char* w3p8 = (unsigned char*)(ws + W3P8_BYTE_OFF);
  unsigned char* seq8 = (unsigned char*)(ws + SEQ8_BYTE_OFF);
  short* h3p  = (short*)(ws + BIG_BYTE_OFF);
  // fp8 w1/w2 live in the head of h3p (dead until win writes h3p, after enc)
  unsigned char* w1p8 = (unsigned char*)h3p;
  unsigned char* w2p8 = w1p8 + 524288;
  float* out  = (float*)d_out;

  pack_w_kernel    <<<WP_TOTAL / 256, 256, 0, stream>>>(w1, w2, w3, w4, w5, wp);
  pack_w_fp8_kernel<<<4608, 256, 0, stream>>>(w1, w2, w3, w1p8, w3p8);
  hid_copy_kernel  <<<1792, 256, 0, stream>>>(hid, seq8);
  enc_kernel       <<<2048, 512, 0, stream>>>(inp, w1p8, b1, w2p8, b2, seq8);
  enc_hi_kernel    <<<224, 256, 0, stream>>>(inp, w1p, b1, w2p, b2, out);
  win_kernel       <<<1024, 512, 0, stream>>>(seq8, w3p8, b3, h3p);
  dec_kernel       <<<1024, 512, 0, stream>>>(h3p, w4p, b4, w5p, b5, out);
}

// Round 11
// 454.170 us; speedup vs baseline: 1.9089x; 1.0257x over previous
//
#include <hip/hip_runtime.h>
#include <hip/hip_bf16.h>
#include <hip/hip_fp8.h>

// SlidingFFAgent: fused 5-layer MLP + sliding window, MFMA pipeline.
// Round 11: hardware v_cvt_pk_fp8_f32 for ALL f32->e4m3 conversions (enc
// stage-A / h1-write / epilogue, hid_copy, pack_w_fp8). Rest identical to r10.

#define DEVI __device__ __forceinline__

typedef float f32x4 __attribute__((ext_vector_type(4)));
typedef short s16x8 __attribute__((ext_vector_type(8)));
typedef short s16x4 __attribute__((ext_vector_type(4)));
typedef long long i64;

#define ROWS 131072
#define SEQ_T 263

// packed bf16 weight offsets (in shorts)
#define W2P_OFF 524288
#define W3P_OFF 655360
#define W4P_OFF 1179648
#define W5P_OFF 1441792
#define WP_TOTAL 1458176

#define W3P8_BYTE_OFF 2916352           // fp8 w3 frags (512KB)
#define SEQ8_BYTE_OFF 3440640           // fp8 seq: 512 ba x 263 x 128B
#define BIG_BYTE_OFF 37388288           // h3p; head doubles as fp8 w1/w2 for enc

DEVI short f2bf(float f) {
  union { __hip_bfloat16 h; short s; } u;
  u.h = __float2bfloat16(f);
  return u.s;
}

DEVI unsigned int f2e4(float f) {
  union { __hip_fp8_e4m3 h; unsigned char c; } u;
  u.h = __hip_fp8_e4m3(f);
  return (unsigned int)u.c;
}

// pack 4 f32 -> 4 e4m3 bytes (hardware cvt_pk when available)
#if __has_builtin(__builtin_amdgcn_cvt_pk_fp8_f32)
DEVI unsigned int pk4e4(float a, float b, float c, float d) {
  int v = 0;
  v = __builtin_amdgcn_cvt_pk_fp8_f32(a, b, v, false);
  v = __builtin_amdgcn_cvt_pk_fp8_f32(c, d, v, true);
  return (unsigned int)v;
}
#else
DEVI unsigned int pk4e4(float a, float b, float c, float d) {
  return f2e4(a) | (f2e4(b) << 8) | (f2e4(c) << 16) | (f2e4(d) << 24);
}
#endif

DEVI f32x4 MFMA(s16x8 a, s16x8 b, f32x4 c) {
  return __builtin_amdgcn_mfma_f32_16x16x32_bf16(a, b, c, 0, 0, 0);
}
DEVI f32x4 MFMA8(i64 a, i64 b, f32x4 c) {
  return __builtin_amdgcn_mfma_f32_16x16x32_fp8_fp8(a, b, c, 0, 0, 0);
}

// ---------------- bf16 weight packing (w1/w2 for enc_hi, w4/w5 for dec) ----------------
__global__ __launch_bounds__(256) void pack_w_kernel(
    const float* __restrict__ w1, const float* __restrict__ w2,
    const float* __restrict__ w3, const float* __restrict__ w4,
    const float* __restrict__ w5, short* __restrict__ wp)
{
  int idx = blockIdx.x * 256 + threadIdx.x;
  const float* src; int sh, Nsrc, local;
  if (idx < W2P_OFF)      { src = w1; sh = 4; Nsrc = 1024; local = idx; }
  else if (idx < W3P_OFF) { src = w2; sh = 5; Nsrc = 128;  local = idx - W2P_OFF; }
  else if (idx < W4P_OFF) { src = w3; sh = 5; Nsrc = 512;  local = idx - W3P_OFF; }
  else if (idx < W5P_OFF) { src = w4; sh = 4; Nsrc = 512;  local = idx - W4P_OFF; }
  else                    { src = w5; sh = 4; Nsrc = 30;   local = idx - W5P_OFF; }
  int j    = local & 7;
  int lane = (local >> 3) & 63;
  int rest = local >> 9;
  int k0   = rest & ((1 << sh) - 1);
  int n0   = rest >> sh;
  int k = (k0 << 5) + ((lane >> 4) << 3) + j;
  int n = (n0 << 4) + (lane & 15);
  float v = (n < Nsrc) ? src[k * Nsrc + n] : 0.f;
  wp[idx] = f2bf(v);
}

// ---------------- fp8 weight packing: 8 elems/thread, u64 stores ----------------
__global__ __launch_bounds__(256) void pack_w_fp8_kernel(
    const float* __restrict__ w1, const float* __restrict__ w2,
    const float* __restrict__ w3,
    unsigned char* __restrict__ wp8, unsigned char* __restrict__ w3p8)
{
  int t = blockIdx.x * 256 + threadIdx.x;   // 147456 total
  const float* src; int nkshift, Nsrc, dt; unsigned char* dst;
  if (t < 65536)      { src = w1; dt = t;         nkshift = 4; Nsrc = 1024; dst = wp8; }
  else if (t < 81920) { src = w2; dt = t - 65536; nkshift = 5; Nsrc = 128;  dst = wp8 + 524288; }
  else                { src = w3; dt = t - 81920; nkshift = 5; Nsrc = 512;  dst = w3p8; }
  int lane = dt & 63;
  int rest = dt >> 6;
  int k0   = rest & ((1 << nkshift) - 1);
  int n0   = rest >> nkshift;
  int kb = (k0 << 5) + ((lane >> 4) << 3);
  int n  = (n0 << 4) + (lane & 15);
  float v[8];
  #pragma unroll
  for (int j = 0; j < 8; ++j) v[j] = src[(kb + j) * Nsrc + n];
  unsigned long long pk = (unsigned long long)pk4e4(v[0], v[1], v[2], v[3])
                        | ((unsigned long long)pk4e4(v[4], v[5], v[6], v[7]) << 32);
  *(unsigned long long*)(dst + (long)dt * 8) = pk;
}

// ---------------- hidden_state -> fp8 seq frames 0..6 (8 elems/thread) ----------------
__global__ __launch_bounds__(256) void hid_copy_kernel(
    const float* __restrict__ hid, unsigned char* __restrict__ seq8)
{
  int t = blockIdx.x * 256 + threadIdx.x;   // 57344 total
  int j = t & 15;          // d>>3
  int r = t >> 4;          // ba*7 + i
  int i = r % 7;
  int ba = r / 7;
  int s = j ^ i;
  const float* src = hid + (r << 7) + (j << 3);
  f32x4 a = *(const f32x4*)src;
  f32x4 b = *(const f32x4*)(src + 4);
  unsigned long long pk = (unsigned long long)pk4e4(a[0], a[1], a[2], a[3])
                        | ((unsigned long long)pk4e4(b[0], b[1], b[2], b[3]) << 32);
  *(unsigned long long*)(seq8 + (ba * SEQ_T + i) * 128 + s * 8) = pk;
}

// ---------------- fp8 encoder: x2 = relu(relu(inp@w1+b1)@w2+b2) -> fp8 seq ----------------
__global__ __launch_bounds__(512, 4) void enc_kernel(
    const float* __restrict__ inp, const unsigned char* __restrict__ w1p8,
    const float* __restrict__ b1, const unsigned char* __restrict__ w2p8,
    const float* __restrict__ b2, unsigned char* __restrict__ seq8)
{
  __shared__ unsigned char As8[32768] __attribute__((aligned(16)));
  __shared__ unsigned char h1q8[32768] __attribute__((aligned(16)));
  const int tid = threadIdx.x;
  const int lane = tid & 63, wv = tid >> 6;     // wave 0..7
  const int l15 = lane & 15, lg = lane >> 4;
  const int rb = blockIdx.x << 6;

  // ---- stage A: f32 rows -> e4m3 LDS [k2][m], read HBM once ----
  #pragma unroll
  for (int it = 0; it < 8; ++it) {
    int g = it * 512 + tid;            // 4096 chunks of 8 elems
    int row = g >> 6, j = g & 63;      // j = k2
    const float* s = inp + (long)(rb + row) * 512 + j * 8;
    f32x4 v0 = *(const f32x4*)s;
    f32x4 v1 = *(const f32x4*)(s + 4);
    unsigned long long pk = (unsigned long long)pk4e4(v0[0], v0[1], v0[2], v0[3])
                          | ((unsigned long long)pk4e4(v1[0], v1[1], v1[2], v1[3]) << 32);
    *(unsigned long long*)(As8 + (j << 9) + ((row ^ (j & 7)) << 3)) = pk;
  }
  __syncthreads();

  f32x4 z = {0.f, 0.f, 0.f, 0.f};
  f32x4 acc2[4] = {z, z, z, z};   // x2 cols wv*16..+16, 4 m-frags, full K

  for (int p = 0; p < 2; ++p) {
    // ---- stage 1: h1^T cols [p*512 + wv*64, +64), C=4 x R=4 ----
    f32x4 acc1[4][4];   // [ci][mi]
    #pragma unroll
    for (int i = 0; i < 4; ++i)
      #pragma unroll
      for (int j = 0; j < 4; ++j) acc1[i][j] = z;

    const unsigned char* wB = w1p8 + (((p * 32 + wv * 4) * 16) << 9) + lane * 8;

    i64 Wc[4];
    #pragma unroll
    for (int ci = 0; ci < 4; ++ci) Wc[ci] = *(const i64*)(wB + ((ci * 16) << 9));

    #pragma unroll 1
    for (int k0 = 0; k0 < 16; ++k0) {
      int kn = (k0 + 1) & 15;
      i64 Wn[4];
      #pragma unroll
      for (int ci = 0; ci < 4; ++ci) Wn[ci] = *(const i64*)(wB + ((ci * 16 + kn) << 9));
      int k2 = k0 * 4 + lg;
      int c = k2 & 7;
      i64 Xc[4];
      #pragma unroll
      for (int mi = 0; mi < 4; ++mi)
        Xc[mi] = *(const i64*)(As8 + (k2 << 9) + (((mi * 16 + l15) ^ c) << 3));
      #pragma unroll
      for (int ci = 0; ci < 4; ++ci)
        #pragma unroll
        for (int mi = 0; mi < 4; ++mi)
          acc1[ci][mi] = MFMA8(Wc[ci], Xc[mi], acc1[ci][mi]);
      #pragma unroll
      for (int ci = 0; ci < 4; ++ci) Wc[ci] = Wn[ci];
    }
    __syncthreads();  // prev pass's stage2 done reading h1q8
    // ---- write h1^T (relu+b1) -> e4m3 h1q8[k2c][m], 4B per (ci,mi) ----
    #pragma unroll
    for (int ci = 0; ci < 4; ++ci) {
      f32x4 bv = *(const f32x4*)(b1 + p * 512 + wv * 64 + ci * 16 + lg * 4);
      int k2c = wv * 8 + ci * 2 + (lg >> 1);
      int half = (lg & 1) << 2;
      #pragma unroll
      for (int mi = 0; mi < 4; ++mi) {
        int m = mi * 16 + l15;
        unsigned int pk = pk4e4(fmaxf(acc1[ci][mi][0] + bv[0], 0.f),
                                fmaxf(acc1[ci][mi][1] + bv[1], 0.f),
                                fmaxf(acc1[ci][mi][2] + bv[2], 0.f),
                                fmaxf(acc1[ci][mi][3] + bv[3], 0.f));
        *(unsigned int*)(h1q8 + (k2c << 9) + (m << 3) + half) = pk;
      }
    }
    __syncthreads();
    // ---- stage 2: acc2 += mfma(w2frag, h1frag), 16 k-steps this pass ----
    const unsigned char* w2B = w2p8 + ((wv * 32 + p * 16) << 9) + lane * 8;
    i64 W2c = *(const i64*)(w2B);
    #pragma unroll 1
    for (int kk = 0; kk < 16; ++kk) {
      int kn = (kk + 1) & 15;
      i64 W2n = *(const i64*)(w2B + (kn << 9));
      i64 X2[4];
      #pragma unroll
      for (int mi = 0; mi < 4; ++mi)
        X2[mi] = *(const i64*)(h1q8 + ((kk * 4 + lg) << 9) + ((mi * 16 + l15) << 3));
      #pragma unroll
      for (int mi = 0; mi < 4; ++mi)
        acc2[mi] = MFMA8(W2c, X2[mi], acc2[mi]);
      W2c = W2n;
    }
  }
  // ---- epilogue: x2^T (relu+b2) -> e4m3 scratch (row-swizzled) -> fp8 seq ----
  __syncthreads();
  unsigned char* scr8 = As8;   // 8KB scratch (As dead)
  {
    f32x4 bv = *(const f32x4*)(b2 + wv * 16 + lg * 4);
    int gsb = wv * 2 + (lg >> 1);
    int off4 = (lg & 1) << 2;
    #pragma unroll
    for (int mi = 0; mi < 4; ++mi) {
      int m = mi * 16 + l15;
      int f7 = ((rb >> 4) + mi + 7) & 7;
      unsigned int pk = pk4e4(fmaxf(acc2[mi][0] + bv[0], 0.f),
                              fmaxf(acc2[mi][1] + bv[1], 0.f),
                              fmaxf(acc2[mi][2] + bv[2], 0.f),
                              fmaxf(acc2[mi][3] + bv[3], 0.f));
      int ls = (gsb ^ f7) ^ (m & 7);
      *(unsigned int*)(scr8 + m * 128 + ls * 8 + off4) = pk;
    }
  }
  __syncthreads();
  #pragma unroll
  for (int it = 0; it < 2; ++it) {
    int c = it * 512 + tid;
    int i = c >> 4, s = c & 15;
    unsigned long long v = *(const unsigned long long*)(scr8 + i * 128 + ((s ^ (i & 7)) << 3));
    int r = rb + i;
    int ba2 = ((r >> 12) << 4) + (r & 15);
    int t = (r >> 4) & 255;
    int f = t + 7;
    *(unsigned long long*)(seq8 + (ba2 * SEQ_T + f) * 128 + (s << 3)) = v;
  }
}

// ---------------- bf16 recompute of window frames (t=249..255) -> output 1 ----------------
__global__ __launch_bounds__(256) void enc_hi_kernel(
    const float* __restrict__ inp, const short* __restrict__ w1p,
    const float* __restrict__ b1, const short* __restrict__ w2p,
    const float* __restrict__ b2, float* __restrict__ out)
{
  __shared__ short As[8192]  __attribute__((aligned(16)));  // [k2 64][m 16] 16B
  __shared__ short h1s[16384] __attribute__((aligned(16))); // [k2c 128][m 16] 16B
  const int tid = threadIdx.x;
  const int lane = tid & 63, wv = tid >> 6;   // wave 0..3
  const int l15 = lane & 15, lg = lane >> 4;
  const int b = blockIdx.x / 7, ti = blockIdx.x % 7;
  const int t = 249 + ti;
  const long row0 = (long)b * 4096 + t * 16;

  #pragma unroll
  for (int it = 0; it < 4; ++it) {
    int c = it * 256 + tid;            // 1024 chunks (16 rows x 64)
    int m = c >> 6, j = c & 63;
    const float* s = inp + (row0 + m) * 512 + j * 8;
    f32x4 v0 = *(const f32x4*)s;
    f32x4 v1 = *(const f32x4*)(s + 4);
    s16x8 o;
    o[0]=f2bf(v0[0]); o[1]=f2bf(v0[1]); o[2]=f2bf(v0[2]); o[3]=f2bf(v0[3]);
    o[4]=f2bf(v1[0]); o[5]=f2bf(v1[1]); o[6]=f2bf(v1[2]); o[7]=f2bf(v1[3]);
    *(s16x8*)((char*)As + (j << 8) + (((m ^ (j & 15)) & 15) << 4)) = o;
  }
  __syncthreads();

  f32x4 z = {0.f, 0.f, 0.f, 0.f};
  f32x4 acc1[16];
  #pragma unroll
  for (int i = 0; i < 16; ++i) acc1[i] = z;
  #pragma unroll 1
  for (int k0 = 0; k0 < 16; ++k0) {
    int k2 = k0 * 4 + lg;
    s16x8 X = *(const s16x8*)((const char*)As + (k2 << 8) + (((l15 ^ (k2 & 15)) & 15) << 4));
    #pragma unroll
    for (int ci = 0; ci < 16; ++ci) {
      s16x8 W = *(const s16x8*)(w1p + (((wv * 16 + ci) * 16 + k0) << 9) + lane * 8);
      acc1[ci] = MFMA(W, X, acc1[ci]);
    }
  }
  #pragma unroll
  for (int ci = 0; ci < 16; ++ci) {
    f32x4 bv = *(const f32x4*)(b1 + wv * 256 + ci * 16 + lg * 4);
    int k2c = wv * 32 + ci * 2 + (lg >> 1);
    int half = (lg & 1) << 3;
    s16x4 o;
    #pragma unroll
    for (int j = 0; j < 4; ++j)
      o[j] = f2bf(fmaxf(acc1[ci][j] + bv[j], 0.f));
    *(s16x4*)((char*)h1s + (k2c << 8) + (l15 << 4) + half) = o;
  }
  __syncthreads();
  f32x4 acc2[2] = {z, z};
  #pragma unroll 1
  for (int kk = 0; kk < 32; ++kk) {
    s16x8 X2 = *(const s16x8*)((const char*)h1s + ((kk * 4 + lg) << 8) + (l15 << 4));
    #pragma unroll
    for (int nf = 0; nf < 2; ++nf) {
      s16x8 W2 = *(const s16x8*)(w2p + (((wv * 2 + nf) * 32 + kk) << 9) + lane * 8);
      acc2[nf] = MFMA(W2, X2, acc2[nf]);
    }
  }
  #pragma unroll
  for (int nf = 0; nf < 2; ++nf) {
    #pragma unroll
    for (int rr = 0; rr < 4; ++rr) {
      int d = (wv * 2 + nf) * 16 + lg * 4 + rr;
      float v = fmaxf(acc2[nf][rr] + b2[d], 0.f);
      out[3932160 + (((b * 16 + l15) * 7 + ti) << 7) + d] = v;
    }
  }
}

// ---------------- fp8 sliding-window GEMM: h3 = relu(wins@w3+b3) -> dec A-frags ----------------
__global__ __launch_bounds__(512, 4) void win_kernel(
    const unsigned char* __restrict__ seq8, const unsigned char* __restrict__ w3p8,
    const float* __restrict__ b3, short* __restrict__ h3p)
{
  __shared__ unsigned char sh8[17280] __attribute__((aligned(16)));  // 135 frames x 128B
  __shared__ short rp[16384] __attribute__((aligned(16)));           // 128x128 bf16 repack
  const int tid = threadIdx.x;
  const int lane = tid & 63, wid = tid >> 6;
  const int wm = wid >> 2, wn = wid & 3;
  const int l15 = lane & 15, lg = lane >> 4;
  const int bid = blockIdx.x;
  const int th = bid & 1, ba = bid >> 1;
  const int t0 = th << 7;

  const unsigned char* gsrc = seq8 + (ba * SEQ_T + t0) * 128;
  #pragma unroll
  for (int i = 0; i < 3; ++i) {
    int c = i * 512 + tid;
    if (c < 1080) *(s16x8*)&sh8[c * 16] = *(const s16x8*)(gsrc + c * 16);
  }
  __syncthreads();

  f32x4 z = {0.f, 0.f, 0.f, 0.f};
  for (int h = 0; h < 2; ++h) {
    f32x4 acc[4][4];
    #pragma unroll
    for (int i = 0; i < 4; ++i)
      #pragma unroll
      for (int j = 0; j < 4; ++j) acc[i][j] = z;

    const unsigned char* bB = w3p8 + (((h * 16 + wn * 4) * 32) << 9) + lane * 8;
    i64 bcur[4];
    #pragma unroll
    for (int nf = 0; nf < 4; ++nf) bcur[nf] = *(const i64*)(bB + ((nf * 32) << 9));

    #pragma unroll 1
    for (int kc = 0; kc < 32; ++kc) {
      int kn = (kc + 1) & 31;
      i64 bnxt[4];
      #pragma unroll
      for (int nf = 0; nf < 4; ++nf) bnxt[nf] = *(const i64*)(bB + ((nf * 32 + kn) << 9));
      int w = kc >> 2;
      int dslot = ((kc & 3) << 2) + lg;
      i64 av[4];
      #pragma unroll
      for (int mf = 0; mf < 4; ++mf) {
        int f = wm * 64 + mf * 16 + l15 + w;
        av[mf] = *(const i64*)(sh8 + f * 128 + ((dslot ^ (f & 7)) << 3));
      }
      #pragma unroll
      for (int nf = 0; nf < 4; ++nf)
        #pragma unroll
        for (int mf = 0; mf < 4; ++mf)
          acc[mf][nf] = MFMA8(av[mf], bcur[nf], acc[mf][nf]);
      #pragma unroll
      for (int nf = 0; nf < 4; ++nf) bcur[nf] = bnxt[nf];
    }

    for (int s = 0; s < 2; ++s) {
      __syncthreads();
      #pragma unroll
      for (int mf = 0; mf < 4; ++mf)
        #pragma unroll
        for (int e = 0; e < 2; ++e) {
          int nf = s * 2 + e;
          float bias = b3[h * 256 + wn * 64 + nf * 16 + l15];
          int lc = wn * 32 + e * 16 + l15;
          #pragma unroll
          for (int rr = 0; rr < 4; ++rr) {
            int row = wm * 64 + mf * 16 + lg * 4 + rr;
            float v = fmaxf(acc[mf][nf][rr] + bias, 0.f);
            int by = ((row << 8) + (lc << 1)) ^ ((row & 7) << 4);
            rp[by >> 1] = f2bf(v);
          }
        }
      __syncthreads();
      #pragma unroll
      for (int it = 0; it < 4; ++it) {
        int c = it * 512 + tid;
        int cl = c & 15, g = (c >> 4) & 3, kq = (c >> 6) & 3, tt = (c >> 8) & 7;
        int row = tt * 16 + cl;
        int by = ((row << 8) + (kq << 6) + (g << 4)) ^ ((row & 7) << 4);
        int k0g = h * 8 + kq * 2 + s;
        int mt = ba * 16 + th * 8 + tt;
        long dst = ((long)((mt * 16 + k0g) * 64 + g * 16 + cl)) << 3;
        *(s16x8*)(h3p + dst) = *(const s16x8*)((const char*)rp + by);
      }
    }
  }
}

// ---------------- decoder: q = relu(h3@w4+b4)@w5+b5 ----------------
__global__ __launch_bounds__(512, 4) void dec_kernel(
    const short* __restrict__ h3p, const short* __restrict__ w4p,
    const float* __restrict__ b4, const short* __restrict__ w5p,
    const float* __restrict__ b5, float* __restrict__ out)
{
  __shared__ short h4s[32768] __attribute__((aligned(16)));
  const int tid = threadIdx.x;
  const int lane = tid & 63, wid = tid >> 6;
  const int wm = wid >> 2, wn = wid & 3;
  const int mf5 = wid;
  const int l15 = lane & 15, lg = lane >> 4;
  const int rb = blockIdx.x << 7;

  f32x4 z = {0.f, 0.f, 0.f, 0.f};
  f32x4 acc5[2] = {z, z};
  const short* aBase = h3p + ((rb >> 4) + wm * 4) * 8192 + lane * 8;

  for (int h = 0; h < 2; ++h) {
    f32x4 acc[4][4];
    #pragma unroll
    for (int i = 0; i < 4; ++i)
      #pragma unroll
      for (int j = 0; j < 4; ++j) acc[i][j] = z;

    const short* bB = w4p + ((h * 16 + wn * 4) * 16) * 512 + lane * 8;
    s16x8 bcur[4];
    #pragma unroll
    for (int nf = 0; nf < 4; ++nf) bcur[nf] = *(const s16x8*)(bB + (nf * 16) * 512);

    #pragma unroll 1
    for (int k0 = 0; k0 < 16; ++k0) {
      int kn = (k0 + 1) & 15;
      s16x8 bnxt[4];
      #pragma unroll
      for (int nf = 0; nf < 4; ++nf) bnxt[nf] = *(const s16x8*)(bB + (nf * 16 + kn) * 512);
      s16x8 av[4];
      #pragma unroll
      for (int mf = 0; mf < 4; ++mf) av[mf] = *(const s16x8*)(aBase + mf * 8192 + k0 * 512);
      #pragma unroll
      for (int nf = 0; nf < 4; ++nf)
        #pragma unroll
        for (int mf = 0; mf < 4; ++mf)
          acc[mf][nf] = MFMA(av[mf], bcur[nf], acc[mf][nf]);
      #pragma unroll
      for (int nf = 0; nf < 4; ++nf) bcur[nf] = bnxt[nf];
    }
    __syncthreads();
    #pragma unroll
    for (int mf = 0; mf < 4; ++mf)
      #pragma unroll
      for (int nf = 0; nf < 4; ++nf) {
        int lc = wn * 64 + nf * 16 + l15;
        float bias = b4[h * 256 + lc];
        #pragma unroll
        for (int rr = 0; rr < 4; ++rr) {
          int row = wm * 64 + mf * 16 + lg * 4 + rr;
          float v = fmaxf(acc[mf][nf][rr] + bias, 0.f);
          int by = ((row << 9) + (lc << 1)) ^ ((row & 7) << 4);
          h4s[by >> 1] = f2bf(v);
        }
      }
    __syncthreads();
    #pragma unroll
    for (int kk = 0; kk < 8; ++kk) {
      int row = mf5 * 16 + l15;
      int by = ((row << 9) + (kk << 6) + (lg << 4)) ^ ((row & 7) << 4);
      s16x8 a0 = *(const s16x8*)((const char*)h4s + by);
      #pragma unroll
      for (int nf = 0; nf < 2; ++nf) {
        s16x8 wb = *(const s16x8*)(w5p + (nf * 16 + h * 8 + kk) * 512 + lane * 8);
        acc5[nf] = MFMA(a0, wb, acc5[nf]);
      }
    }
  }
  #pragma unroll
  for (int nf = 0; nf < 2; ++nf) {
    int col = nf * 16 + l15;
    if (col < 30) {
      float bias = b5[col];
      #pragma unroll
      for (int rr = 0; rr < 4; ++rr) {
        int row_ = rb + mf5 * 16 + lg * 4 + rr;
        int t = row_ & 255;
        int ba2 = row_ >> 8;
        int orow = (((ba2 >> 4) << 8) + t) * 16 + (ba2 & 15);
        out[orow * 30 + col] = acc5[nf][rr] + bias;
      }
    }
  }
}

extern "C" void kernel_launch(void* const* d_in, const int* in_sizes, int n_in,
                              void* d_out, int out_size, void* d_ws, size_t ws_size,
                              hipStream_t stream) {
  const float* inp = (const float*)d_in[0];
  const float* hid = (const float*)d_in[1];
  const float* w1  = (const float*)d_in[2];
  const float* b1  = (const float*)d_in[3];
  const float* w2  = (const float*)d_in[4];
  const float* b2  = (const float*)d_in[5];
  const float* w3  = (const float*)d_in[6];
  const float* b3  = (const float*)d_in[7];
  const float* w4  = (const float*)d_in[8];
  const float* b4  = (const float*)d_in[9];
  const float* w5  = (const float*)d_in[10];
  const float* b5  = (const float*)d_in[11];

  char* ws = (char*)d_ws;
  short* wp   = (short*)ws;
  short* w1p  = wp;
  short* w2p  = wp + W2P_OFF;
  short* w4p  = wp + W4P_OFF;
  short* w5p  = wp + W5P_OFF;
  unsigned char* w3p8 = (unsigned char*)(ws + W3P8_BYTE_OFF);
  unsigned char* seq8 = (unsigned char*)(ws + SEQ8_BYTE_OFF);
  short* h3p  = (short*)(ws + BIG_BYTE_OFF);
  unsigned char* w1p8 = (unsigned char*)h3p;
  unsigned char* w2p8 = w1p8 + 524288;
  float* out  = (float*)d_out;

  pack_w_kernel    <<<WP_TOTAL / 256, 256, 0, stream>>>(w1, w2, w3, w4, w5, wp);
  pack_w_fp8_kernel<<<576, 256, 0, stream>>>(w1, w2, w3, w1p8, w3p8);
  hid_copy_kernel  <<<224, 256, 0, stream>>>(hid, seq8);
  enc_kernel       <<<2048, 512, 0, stream>>>(inp, w1p8, b1, w2p8, b2, seq8);
  enc_hi_kernel    <<<224, 256, 0, stream>>>(inp, w1p, b1, w2p, b2, out);
  win_kernel       <<<1024, 512, 0, stream>>>(seq8, w3p8, b3, h3p);
  dec_kernel       <<<1024, 512, 0, stream>>>(h3p, w4p, b4, w5p, b5, out);
}